// Round 2
// baseline (357.417 us; speedup 1.0000x reference)
//
#include <hip/hip_runtime.h>
#include <hip/hip_fp16.h>

// InvariantGaussianAttention, MI355X (gfx950)
// B=2 N=384 CS=384 CZ=128 H=8 CH=16 G=2 P=8 CZ4=32
#define NB   2
#define NN   384
#define NCS  384
#define NCZ  128
#define NH   8
#define NCH  16
#define NG   2
#define NP   8
#define NCZ4 32
#define BN   (NB*NN)   // 768
#define LINW 768       // q(128)|k(128)|v(128)|qg(96)|kg(96)|vp(192)

typedef _Float16 f16x2_t __attribute__((ext_vector_type(2)));

static __device__ __forceinline__ float fdot2a(unsigned int a, unsigned int b, float c) {
#if __has_builtin(__builtin_amdgcn_fdot2)
    return __builtin_amdgcn_fdot2(__builtin_bit_cast(f16x2_t, a),
                                  __builtin_bit_cast(f16x2_t, b), c, false);
#else
    __half2 ah = __builtin_bit_cast(__half2, a);
    __half2 bh = __builtin_bit_cast(__half2, b);
    float2 af = __half22float2(ah), bf = __half22float2(bh);
    return fmaf(af.y, bf.y, fmaf(af.x, bf.x, c));
#endif
}

// ---------------- K1: fused row linear  lin = s @ [Wq|Wk|Wv|Wqg|Wkg|Wvp] ----------------
__global__ void __launch_bounds__(256)
k_rowlin(const float* __restrict__ s,
         const float* __restrict__ Wq, const float* __restrict__ Wk,
         const float* __restrict__ Wv,
         const float* __restrict__ Wqg, const float* __restrict__ bqg,
         const float* __restrict__ Wkg, const float* __restrict__ bkg,
         const float* __restrict__ Wvp, const float* __restrict__ bvp,
         float* __restrict__ lin) {
    __shared__ float sl[8][NCS];   // 12 KB
    int t  = threadIdx.x;
    int r0 = blockIdx.x * 8;
    for (int idx = t; idx < 8*NCS; idx += 256)
        sl[idx / NCS][idx % NCS] = s[(size_t)(r0 + idx/NCS)*NCS + (idx % NCS)];
    __syncthreads();
    int col = blockIdx.y * 256 + t;
    const float* W; int sw; float bias = 0.f;
    if      (col < 128) { W = Wq  + col;        sw = 128; }
    else if (col < 256) { W = Wk  + (col-128);  sw = 128; }
    else if (col < 384) { W = Wv  + (col-256);  sw = 128; }
    else if (col < 480) { W = Wqg + (col-384);  sw = 96;  bias = bqg[col-384]; }
    else if (col < 576) { W = Wkg + (col-480);  sw = 96;  bias = bkg[col-480]; }
    else                { W = Wvp + (col-576);  sw = 192; bias = bvp[col-576]; }
    float a[8];
    #pragma unroll
    for (int r = 0; r < 8; ++r) a[r] = 0.f;
    #pragma unroll 4
    for (int c = 0; c < NCS; ++c) {
        float w = W[(size_t)c*sw];
        #pragma unroll
        for (int r = 0; r < 8; ++r) a[r] = fmaf(sl[r][c], w, a[r]);
    }
    #pragma unroll
    for (int r = 0; r < 8; ++r)
        lin[(size_t)(r0+r)*LINW + col] = a[r] + bias;
}

// ---------------- K2: to_global (mu, Sigma), rotated value points, + wprep block ----------------
__global__ void k_geom(const float* __restrict__ lin, const float* __restrict__ rot,
                       const float* __restrict__ trans, const float* __restrict__ lm,
                       const float* __restrict__ sc,
                       const float* __restrict__ Wb, const float* __restrict__ Wdz,
                       float* __restrict__ qmu, float* __restrict__ qsig,
                       float* __restrict__ kmu, float* __restrict__ ksig,
                       float* __restrict__ vpg, unsigned int* __restrict__ wc) {
    int bn = blockIdx.x, t = threadIdx.x;
    if (bn == BN) {   // weight prep: pack [Wb|Wdz] columns as half2 c-pairs
        for (int e = t; e < 40*64; e += 64) {
            int oc = e >> 6, c2 = e & 63;
            float w0, w1;
            if (oc < 8) { w0 = Wb[(2*c2)*NH + oc];    w1 = Wb[(2*c2+1)*NH + oc]; }
            else        { int c4 = oc-8;
                          w0 = Wdz[(2*c2)*NCZ4 + c4]; w1 = Wdz[(2*c2+1)*NCZ4 + c4]; }
            __half2 h = __floats2half2_rn(w0, w1);
            wc[e] = __builtin_bit_cast(unsigned int, h);
        }
        return;
    }
    __shared__ float R[9], T[3], A[3], Bs[3];
    if (t < 9) R[t] = rot[bn*9 + t];
    if (t < 3) { T[t] = trans[bn*3+t]; A[t] = lm[bn*3+t]; Bs[t] = sc[bn*3+t]; }
    __syncthreads();
    {   // value points: one per thread (h=t/8, p=t&7)
        int h = t >> 3, p = t & 7;
        const float* vr = lin + (size_t)bn*LINW + 576 + h*24 + p*3;
        float x = vr[0], y = vr[1], z = vr[2];
        float* d = vpg + (size_t)bn*(NH*NP*3) + h*24 + p*3;
        d[0] = R[0]*x + R[1]*y + R[2]*z + T[0];
        d[1] = R[3]*x + R[4]*y + R[5]*z + T[1];
        d[2] = R[6]*x + R[7]*y + R[8]*z + T[2];
    }
    if (t < 32) {
        int side = t >> 4, item = t & 15;      // item = h*2+g
        const float* raw = lin + (size_t)bn*LINW + (side ? 480 : 384) + item*6;
        float u0 = tanhf(raw[0])*3.f, u1 = tanhf(raw[1])*3.f, u2 = tanhf(raw[2])*3.f;
        float e0 = Bs[0] + tanhf(raw[3])*2.f;
        float e1 = Bs[1] + tanhf(raw[4])*2.f;
        float e2 = Bs[2] + tanhf(raw[5])*2.f;
        float sl0 = fmaxf(expf(e0), 1e-6f);
        float sl1 = fmaxf(expf(e1), 1e-6f);
        float sl2 = fmaxf(expf(e2), 1e-6f);
        float p0 = A[0] + u0*sl0, p1 = A[1] + u1*sl1, p2 = A[2] + u2*sl2;
        float mu0 = R[0]*p0 + R[1]*p1 + R[2]*p2 + T[0];
        float mu1 = R[3]*p0 + R[4]*p1 + R[5]*p2 + T[1];
        float mu2 = R[6]*p0 + R[7]*p1 + R[8]*p2 + T[2];
        float v0 = expf(2.f*e0), v1 = expf(2.f*e1), v2 = expf(2.f*e2);
        float s00 = R[0]*R[0]*v0 + R[1]*R[1]*v1 + R[2]*R[2]*v2;
        float s01 = R[0]*R[3]*v0 + R[1]*R[4]*v1 + R[2]*R[5]*v2;
        float s02 = R[0]*R[6]*v0 + R[1]*R[7]*v1 + R[2]*R[8]*v2;
        float s11 = R[3]*R[3]*v0 + R[4]*R[4]*v1 + R[5]*R[5]*v2;
        float s12 = R[3]*R[6]*v0 + R[4]*R[7]*v1 + R[5]*R[8]*v2;
        float s22 = R[6]*R[6]*v0 + R[7]*R[7]*v1 + R[8]*R[8]*v2;
        float* mud = (side ? kmu : qmu) + (size_t)bn*48 + item*3;
        mud[0]=mu0; mud[1]=mu1; mud[2]=mu2;
        float* sgd = (side ? ksig : qsig) + (size_t)bn*96 + item*6;
        sgd[0]=s00; sgd[1]=s01; sgd[2]=s02; sgd[3]=s11; sgd[4]=s12; sgd[5]=s22;
    }
}

// ---------------- K3: fused attention, one block per (b,i) ----------------
// Structure: issue chunk-0 z prefetch -> phase0 (qk+geo for ALL j) -> chunk loop
// { regs->LDS f16, issue next prefetch, barrier, z-dots += logits / pzl, barrier }
// -> softmax -> weighted accumulation -> cat row.
__global__ void __launch_bounds__(256)
k_attn(const float* __restrict__ z, const float* __restrict__ mask,
       const float* __restrict__ rot, const float* __restrict__ trans,
       const float* __restrict__ lin,
       const float* __restrict__ qmu, const float* __restrict__ qsig,
       const float* __restrict__ kmu, const float* __restrict__ ksig,
       const float* __restrict__ vpg, const unsigned int* __restrict__ wc,
       const float* __restrict__ bb, const float* __restrict__ bdz,
       const float* __restrict__ gsc, const float* __restrict__ gbi,
       float* __restrict__ cat) {
    __shared__ float  logits[NH][NN];           // 12 KB
    __shared__ unsigned short zh[24][128];      // 6 KB (f16 z chunk)
    __shared__ __half pzl[NN][36];              // 27.65 KB (pz row, padded stride)
    __shared__ float  qrow[128];
    __shared__ float  qmu_s[48], qsig_s[96];
    __shared__ float  Rm[9], Tv[3];
    __shared__ float  aH[NH], bH[NH];
    __shared__ float  maskI;

    int t  = threadIdx.x;
    int b  = blockIdx.x / NN, i = blockIdx.x % NN;
    int bi = b*NN + i;
    const float* zbase = z + (size_t)bi*NN*NCZ;

    // ---- issue chunk-0 prefetch FIRST (latency hides under phase 0) ----
    float4 pre0 = *reinterpret_cast<const float4*>(zbase +    0 + t*4);
    float4 pre1 = *reinterpret_cast<const float4*>(zbase + 1024 + t*4);
    float4 pre2 = *reinterpret_cast<const float4*>(zbase + 2048 + t*4);

    // ---- stage per-row scalars ----
    if (t < 128) qrow[t] = lin[(size_t)bi*LINW + t];
    if (t < 48)  qmu_s[t] = qmu[(size_t)bi*48 + t];
    if (t >= 64 && t < 160) qsig_s[t-64] = qsig[(size_t)bi*96 + (t-64)];
    if (t >= 160 && t < 169) Rm[t-160] = rot[bi*9 + (t-160)];
    if (t >= 169 && t < 172) Tv[t-169] = trans[bi*3 + (t-169)];
    if (t >= 176 && t < 184) {
        int h = t-176;
        float x = gsc[h];
        aH[h] = (x > 20.f) ? x : log1pf(expf(x));
        bH[h] = gbi[h];
    }
    if (t == 255) maskI = mask[bi];
    __syncthreads();

    // ---- phase 0: qk + geo NLL + mask + bias for ALL j (init logits) ----
    {
        int h = t >> 5, lane = t & 31;
        float qv[16];
        #pragma unroll
        for (int d = 0; d < 16; ++d) qv[d] = qrow[h*16 + d];
        float qm[6], qs[12];
        #pragma unroll
        for (int e = 0; e < 6; ++e)  qm[e] = qmu_s[h*6 + e];
        #pragma unroll
        for (int e = 0; e < 12; ++e) qs[e] = qsig_s[h*12 + e];
        float ascale = aH[h], hbias = bH[h], mI = maskI;
        for (int jj = 0; jj < 12; ++jj) {
            int j = lane + jj*32;
            size_t jrow = (size_t)(b*NN + j);
            const float* kp = lin + jrow*LINW + 128 + h*NCH;
            float4 k0 = *(const float4*)(kp);
            float4 k1 = *(const float4*)(kp+4);
            float4 k2 = *(const float4*)(kp+8);
            float4 k3 = *(const float4*)(kp+12);
            float qk = qv[0]*k0.x + qv[1]*k0.y + qv[2]*k0.z + qv[3]*k0.w
                     + qv[4]*k1.x + qv[5]*k1.y + qv[6]*k1.z + qv[7]*k1.w
                     + qv[8]*k2.x + qv[9]*k2.y + qv[10]*k2.z + qv[11]*k2.w
                     + qv[12]*k3.x + qv[13]*k3.y + qv[14]*k3.z + qv[15]*k3.w;
            float geo = 0.f;
            #pragma unroll
            for (int g = 0; g < NG; ++g) {
                const float* km = kmu + jrow*48 + h*6 + g*3;
                const float* ks = ksig + jrow*96 + h*12 + g*6;
                float d0 = qm[g*3+0] - km[0];
                float d1 = qm[g*3+1] - km[1];
                float d2 = qm[g*3+2] - km[2];
                float s00 = qs[g*6+0] + ks[0];
                float s01 = qs[g*6+1] + ks[1];
                float s02 = qs[g*6+2] + ks[2];
                float s11 = qs[g*6+3] + ks[3];
                float s12 = qs[g*6+4] + ks[4];
                float s22 = qs[g*6+5] + ks[5];
                float l00 = fmaxf(s00, 1e-8f);
                float i00 = rsqrtf(l00);
                float l10 = s01*i00, l20 = s02*i00;
                float l11 = fmaxf(s11 - l10*l10, 1e-8f);
                float i11 = rsqrtf(l11);
                float l21 = (s12 - l20*l10)*i11;
                float l22 = fmaxf(s22 - l20*l20 - l21*l21, 1e-8f);
                float i22 = rsqrtf(l22);
                float ld = __logf(l00) + __logf(l11) + __logf(l22);
                float y0 = d0*i00;
                float y1 = (d1 - l10*y0)*i11;
                float y2 = (d2 - l20*y0 - l21*y1)*i22;
                geo += -0.5f*(y0*y0 + y1*y1 + y2*y2 + ld);
            }
            float m2 = mI * mask[b*NN + j];
            logits[h][j] = qk*0.25f + ascale*(geo*m2) + hbias + (1.f - m2)*(-100000.f);
        }
    }

    // ---- chunk loop: z-dots with register prefetch ----
    int oc = t % 40, g6 = t / 40;   // 240 workers: oc in [0,40), 6 j-groups of 4
    float biasv = 0.f;
    if (t < 240) biasv = (oc < 8) ? bb[oc] : bdz[oc-8];
    const unsigned int* wrow = wc + oc*64;

    #pragma unroll 1
    for (int ch = 0; ch < 16; ++ch) {
        int j0 = ch*24;
        // regs -> LDS (f16). Uses pre* => compiler waits the matching vmcnt only.
        {
            int idx = t*4;
            __half2* d0 = reinterpret_cast<__half2*>(&zh[idx>>7][idx&127]);
            d0[0] = __floats2half2_rn(pre0.x, pre0.y);
            d0[1] = __floats2half2_rn(pre0.z, pre0.w);
            int idx1 = idx + 1024;
            __half2* d1 = reinterpret_cast<__half2*>(&zh[idx1>>7][idx1&127]);
            d1[0] = __floats2half2_rn(pre1.x, pre1.y);
            d1[1] = __floats2half2_rn(pre1.z, pre1.w);
            int idx2 = idx + 2048;
            __half2* d2 = reinterpret_cast<__half2*>(&zh[idx2>>7][idx2&127]);
            d2[0] = __floats2half2_rn(pre2.x, pre2.y);
            d2[1] = __floats2half2_rn(pre2.z, pre2.w);
        }
        // issue next chunk's prefetch; stays in flight across the barrier
        if (ch < 15) {
            const float* zp = zbase + (size_t)(j0 + 24)*NCZ;
            pre0 = *reinterpret_cast<const float4*>(zp +    0 + t*4);
            pre1 = *reinterpret_cast<const float4*>(zp + 1024 + t*4);
            pre2 = *reinterpret_cast<const float4*>(zp + 2048 + t*4);
        }
        __syncthreads();
        if (t < 240) {
            float a0=0.f, a1=0.f, a2=0.f, a3=0.f;
            int jb = g6*4;
            #pragma unroll
            for (int q = 0; q < 16; ++q) {
                uint4 wv = *reinterpret_cast<const uint4*>(wrow + q*4);
                uint4 z0 = *reinterpret_cast<const uint4*>(&zh[jb+0][q*8]);
                uint4 z1 = *reinterpret_cast<const uint4*>(&zh[jb+1][q*8]);
                uint4 z2 = *reinterpret_cast<const uint4*>(&zh[jb+2][q*8]);
                uint4 z3 = *reinterpret_cast<const uint4*>(&zh[jb+3][q*8]);
                a0 = fdot2a(z0.x, wv.x, a0); a0 = fdot2a(z0.y, wv.y, a0);
                a0 = fdot2a(z0.z, wv.z, a0); a0 = fdot2a(z0.w, wv.w, a0);
                a1 = fdot2a(z1.x, wv.x, a1); a1 = fdot2a(z1.y, wv.y, a1);
                a1 = fdot2a(z1.z, wv.z, a1); a1 = fdot2a(z1.w, wv.w, a1);
                a2 = fdot2a(z2.x, wv.x, a2); a2 = fdot2a(z2.y, wv.y, a2);
                a2 = fdot2a(z2.z, wv.z, a2); a2 = fdot2a(z2.w, wv.w, a2);
                a3 = fdot2a(z3.x, wv.x, a3); a3 = fdot2a(z3.y, wv.y, a3);
                a3 = fdot2a(z3.z, wv.z, a3); a3 = fdot2a(z3.w, wv.w, a3);
            }
            if (oc < 8) {
                logits[oc][j0+jb+0] += a0 + biasv;
                logits[oc][j0+jb+1] += a1 + biasv;
                logits[oc][j0+jb+2] += a2 + biasv;
                logits[oc][j0+jb+3] += a3 + biasv;
            } else {
                int c4 = oc - 8;
                pzl[j0+jb+0][c4] = __float2half(a0 + biasv);
                pzl[j0+jb+1][c4] = __float2half(a1 + biasv);
                pzl[j0+jb+2][c4] = __float2half(a2 + biasv);
                pzl[j0+jb+3][c4] = __float2half(a3 + biasv);
            }
        }
        __syncthreads();
    }

    // --- softmax per head (32 lanes per head) ---
    int h = t >> 5, lane = t & 31;
    float mx = -3.4e38f;
    #pragma unroll
    for (int jj = 0; jj < 12; ++jj) mx = fmaxf(mx, logits[h][lane + jj*32]);
    #pragma unroll
    for (int m = 16; m >= 1; m >>= 1) mx = fmaxf(mx, __shfl_xor(mx, m, 64));
    float se = 0.f;
    #pragma unroll
    for (int jj = 0; jj < 12; ++jj) {
        int j = lane + jj*32;
        float e = __expf(logits[h][j] - mx);
        logits[h][j] = e;
        se += e;
    }
    #pragma unroll
    for (int m = 16; m >= 1; m >>= 1) se += __shfl_xor(se, m, 64);
    float inv = 1.f / se;

    // --- pass 2: o / opt / opair accumulation ---
    float o[16], op[24], opa[32];
    #pragma unroll
    for (int d = 0; d < 16; ++d) o[d] = 0.f;
    #pragma unroll
    for (int e = 0; e < 24; ++e) op[e] = 0.f;
    #pragma unroll
    for (int c = 0; c < 32; ++c) opa[c] = 0.f;

    for (int jj = 0; jj < 12; ++jj) {
        int j = lane + jj*32;
        float w = logits[h][j] * inv;
        size_t jrow = (size_t)(b*NN + j);
        const float* vp = lin + jrow*LINW + 256 + h*NCH;
        float vv[16];
        *reinterpret_cast<float4*>(&vv[0])  = *(const float4*)(vp);
        *reinterpret_cast<float4*>(&vv[4])  = *(const float4*)(vp+4);
        *reinterpret_cast<float4*>(&vv[8])  = *(const float4*)(vp+8);
        *reinterpret_cast<float4*>(&vv[12]) = *(const float4*)(vp+12);
        #pragma unroll
        for (int d = 0; d < 16; ++d) o[d] = fmaf(w, vv[d], o[d]);
        const float* vg = vpg + jrow*(NH*NP*3) + h*24;
        float gg[24];
        #pragma unroll
        for (int q4 = 0; q4 < 6; ++q4)
            *reinterpret_cast<float4*>(&gg[q4*4]) = *(const float4*)(vg + q4*4);
        #pragma unroll
        for (int e = 0; e < 24; ++e) op[e] = fmaf(w, gg[e], op[e]);
        const __half2* pzp = reinterpret_cast<const __half2*>(&pzl[j][0]);
        #pragma unroll
        for (int c2 = 0; c2 < 16; ++c2) {
            float2 pf = __half22float2(pzp[c2]);
            opa[2*c2]   = fmaf(w, pf.x, opa[2*c2]);
            opa[2*c2+1] = fmaf(w, pf.y, opa[2*c2+1]);
        }
    }
    // butterfly reduce across the 32 lanes of this head
    #pragma unroll
    for (int m = 16; m >= 1; m >>= 1) {
        #pragma unroll
        for (int d = 0; d < 16; ++d) o[d] += __shfl_xor(o[d], m, 64);
        #pragma unroll
        for (int e = 0; e < 24; ++e) op[e] += __shfl_xor(op[e], m, 64);
        #pragma unroll
        for (int c = 0; c < 32; ++c) opa[c] += __shfl_xor(opa[c], m, 64);
    }
    if (lane == 0) {
        float* cp = cat + (size_t)bi*640;
        #pragma unroll
        for (int d = 0; d < 16; ++d) cp[h*16 + d] = o[d];
        #pragma unroll
        for (int p = 0; p < 8; ++p) {
            float x  = op[p*3+0] - Tv[0];
            float y  = op[p*3+1] - Tv[1];
            float zz = op[p*3+2] - Tv[2];
            float l0 = Rm[0]*x + Rm[3]*y + Rm[6]*zz;   // R^T * (opt - trans)
            float l1 = Rm[1]*x + Rm[4]*y + Rm[7]*zz;
            float l2 = Rm[2]*x + Rm[5]*y + Rm[8]*zz;
            cp[128 + h*24 + p*3 + 0] = l0;
            cp[128 + h*24 + p*3 + 1] = l1;
            cp[128 + h*24 + p*3 + 2] = l2;
            cp[320 + h*8 + p] = sqrtf(l0*l0 + l1*l1 + l2*l2 + 1e-8f);
        }
        #pragma unroll
        for (int c = 0; c < 32; ++c) cp[384 + h*32 + c] = opa[c];
    }
}

// ---------------- K4: out = cat @ Wout + bout ----------------
__global__ void __launch_bounds__(192)
k_out(const float* __restrict__ cat, const float* __restrict__ Wout,
      const float* __restrict__ bout, float* __restrict__ out) {
    __shared__ float cl[4][640];   // 10 KB
    int t  = threadIdx.x;
    int r0 = blockIdx.x * 4;
    for (int idx = t; idx < 4*640; idx += 192)
        cl[idx/640][idx%640] = cat[(size_t)(r0 + idx/640)*640 + (idx%640)];
    __syncthreads();
    int col = blockIdx.y * 192 + t;
    float a0=0.f, a1=0.f, a2=0.f, a3=0.f;
    #pragma unroll 4
    for (int c = 0; c < 640; ++c) {
        float w = Wout[(size_t)c*NCS + col];
        a0 = fmaf(cl[0][c], w, a0);
        a1 = fmaf(cl[1][c], w, a1);
        a2 = fmaf(cl[2][c], w, a2);
        a3 = fmaf(cl[3][c], w, a3);
    }
    float bv = bout[col];
    out[(size_t)(r0+0)*NCS + col] = a0 + bv;
    out[(size_t)(r0+1)*NCS + col] = a1 + bv;
    out[(size_t)(r0+2)*NCS + col] = a2 + bv;
    out[(size_t)(r0+3)*NCS + col] = a3 + bv;
}

extern "C" void kernel_launch(void* const* d_in, const int* in_sizes, int n_in,
                              void* d_out, int out_size, void* d_ws, size_t ws_size,
                              hipStream_t stream) {
    const float* s    = (const float*)d_in[0];
    const float* z    = (const float*)d_in[1];
    const float* mask = (const float*)d_in[2];
    const float* rot  = (const float*)d_in[3];
    const float* trans= (const float*)d_in[4];
    const float* lm   = (const float*)d_in[5];
    const float* sc   = (const float*)d_in[6];
    const float* Wq   = (const float*)d_in[7];
    const float* Wk   = (const float*)d_in[8];
    const float* Wv   = (const float*)d_in[9];
    const float* Wb   = (const float*)d_in[10];
    const float* bb   = (const float*)d_in[11];
    const float* Wdz  = (const float*)d_in[12];
    const float* bdz  = (const float*)d_in[13];
    const float* Wqg  = (const float*)d_in[14];
    const float* bqg  = (const float*)d_in[15];
    const float* Wkg  = (const float*)d_in[16];
    const float* bkg  = (const float*)d_in[17];
    const float* Wvp  = (const float*)d_in[18];
    const float* bvp  = (const float*)d_in[19];
    const float* gsc  = (const float*)d_in[20];
    const float* gbi  = (const float*)d_in[21];
    const float* Wout = (const float*)d_in[22];
    const float* bout = (const float*)d_in[23];
    float* out = (float*)d_out;

    float* ws   = (float*)d_ws;
    float* lin  = ws;                    // 768*768      = 589824
    float* qmu  = lin  + 589824;         // 768*48       = 36864
    float* qsig = qmu  + 36864;          // 768*96       = 73728
    float* kmu  = qsig + 73728;          // 36864
    float* ksig = kmu  + 36864;          // 73728
    float* vpg  = ksig + 73728;          // 768*192      = 147456
    float* cat  = vpg  + 147456;         // 768*640      = 491520
    unsigned int* wc = (unsigned int*)(cat + 491520);   // 40*64 = 2560 u32

    k_rowlin<<<dim3(96, 3), 256, 0, stream>>>(s, Wq, Wk, Wv, Wqg, bqg, Wkg, bkg,
                                              Wvp, bvp, lin);
    k_geom<<<BN + 1, 64, 0, stream>>>(lin, rot, trans, lm, sc, Wb, Wdz,
                                      qmu, qsig, kmu, ksig, vpg, wc);
    k_attn<<<BN, 256, 0, stream>>>(z, mask, rot, trans, lin, qmu, qsig, kmu, ksig,
                                   vpg, wc, bb, bdz, gsc, gbi, cat);
    k_out<<<dim3(192, 2), 192, 0, stream>>>(cat, Wout, bout, out);
}

// Round 3
// 192.217 us; speedup vs baseline: 1.8594x; 1.8594x over previous
//
#include <hip/hip_runtime.h>
#include <hip/hip_fp16.h>

// InvariantGaussianAttention, MI355X (gfx950)
// B=2 N=384 CS=384 CZ=128 H=8 CH=16 G=2 P=8 CZ4=32
#define NB   2
#define NN   384
#define NCS  384
#define NCZ  128
#define NH   8
#define NCH  16
#define NG   2
#define NP   8
#define NCZ4 32
#define BN   (NB*NN)   // 768
#define LINW 768       // q(128)|k(128)|v(128)|qg(96)|kg(96)|vp(192)

typedef _Float16 f16x2_t __attribute__((ext_vector_type(2)));

static __device__ __forceinline__ float fdot2a(unsigned int a, unsigned int b, float c) {
#if __has_builtin(__builtin_amdgcn_fdot2)
    return __builtin_amdgcn_fdot2(__builtin_bit_cast(f16x2_t, a),
                                  __builtin_bit_cast(f16x2_t, b), c, false);
#else
    __half2 ah = __builtin_bit_cast(__half2, a);
    __half2 bh = __builtin_bit_cast(__half2, b);
    float2 af = __half22float2(ah), bf = __half22float2(bh);
    return fmaf(af.y, bf.y, fmaf(af.x, bf.x, c));
#endif
}

// ---------------- K0: pack [Wb | Wdz] columns as half2 (c-pairs) ----------------
__global__ void k_wprep(const float* __restrict__ Wb, const float* __restrict__ Wdz,
                        unsigned int* __restrict__ wc) {
    int t = threadIdx.x;
    for (int e = t; e < 40*64; e += 256) {
        int oc = e >> 6, c2 = e & 63;
        float w0, w1;
        if (oc < 8) { w0 = Wb[(2*c2)*NH + oc];       w1 = Wb[(2*c2+1)*NH + oc]; }
        else        { int c4 = oc-8;
                      w0 = Wdz[(2*c2)*NCZ4 + c4];    w1 = Wdz[(2*c2+1)*NCZ4 + c4]; }
        __half2 h = __floats2half2_rn(w0, w1);
        wc[e] = __builtin_bit_cast(unsigned int, h);
    }
}

// ---------------- K1: fused row linear  lin = s @ [Wq|Wk|Wv|Wqg|Wkg|Wvp] ----------------
__global__ void k_rowlin(const float* __restrict__ s,
                         const float* __restrict__ Wq, const float* __restrict__ Wk,
                         const float* __restrict__ Wv,
                         const float* __restrict__ Wqg, const float* __restrict__ bqg,
                         const float* __restrict__ Wkg, const float* __restrict__ bkg,
                         const float* __restrict__ Wvp, const float* __restrict__ bvp,
                         float* __restrict__ lin) {
    __shared__ float sl[4][NCS];
    int t  = threadIdx.x;
    int r0 = blockIdx.x * 4;
    for (int idx = t; idx < 4*NCS; idx += 256)
        sl[idx / NCS][idx % NCS] = s[(size_t)(r0 + idx/NCS)*NCS + (idx % NCS)];
    __syncthreads();
    int col = blockIdx.y * 256 + t;
    const float* W; int sw; float bias = 0.f;
    if      (col < 128) { W = Wq  + col;        sw = 128; }
    else if (col < 256) { W = Wk  + (col-128);  sw = 128; }
    else if (col < 384) { W = Wv  + (col-256);  sw = 128; }
    else if (col < 480) { W = Wqg + (col-384);  sw = 96;  bias = bqg[col-384]; }
    else if (col < 576) { W = Wkg + (col-480);  sw = 96;  bias = bkg[col-480]; }
    else                { W = Wvp + (col-576);  sw = 192; bias = bvp[col-576]; }
    float a0=0.f, a1=0.f, a2=0.f, a3=0.f;
    for (int c = 0; c < NCS; ++c) {
        float w = W[(size_t)c*sw];
        a0 = fmaf(sl[0][c], w, a0);
        a1 = fmaf(sl[1][c], w, a1);
        a2 = fmaf(sl[2][c], w, a2);
        a3 = fmaf(sl[3][c], w, a3);
    }
    lin[(size_t)(r0+0)*LINW + col] = a0 + bias;
    lin[(size_t)(r0+1)*LINW + col] = a1 + bias;
    lin[(size_t)(r0+2)*LINW + col] = a2 + bias;
    lin[(size_t)(r0+3)*LINW + col] = a3 + bias;
}

// ---------------- K2: to_global (mu, Sigma) + rotated value points ----------------
__global__ void k_geom(const float* __restrict__ lin, const float* __restrict__ rot,
                       const float* __restrict__ trans, const float* __restrict__ lm,
                       const float* __restrict__ sc,
                       float* __restrict__ qmu, float* __restrict__ qsig,
                       float* __restrict__ kmu, float* __restrict__ ksig,
                       float* __restrict__ vpg) {
    int bn = blockIdx.x, t = threadIdx.x;
    __shared__ float R[9], T[3], A[3], Bs[3];
    if (t < 9) R[t] = rot[bn*9 + t];
    if (t < 3) { T[t] = trans[bn*3+t]; A[t] = lm[bn*3+t]; Bs[t] = sc[bn*3+t]; }
    __syncthreads();
    {   // value points: one per thread (h=t/8, p=t&7)
        int h = t >> 3, p = t & 7;
        const float* vr = lin + (size_t)bn*LINW + 576 + h*24 + p*3;
        float x = vr[0], y = vr[1], z = vr[2];
        float* d = vpg + (size_t)bn*(NH*NP*3) + h*24 + p*3;
        d[0] = R[0]*x + R[1]*y + R[2]*z + T[0];
        d[1] = R[3]*x + R[4]*y + R[5]*z + T[1];
        d[2] = R[6]*x + R[7]*y + R[8]*z + T[2];
    }
    if (t < 32) {
        int side = t >> 4, item = t & 15;      // item = h*2+g
        const float* raw = lin + (size_t)bn*LINW + (side ? 480 : 384) + item*6;
        float u0 = tanhf(raw[0])*3.f, u1 = tanhf(raw[1])*3.f, u2 = tanhf(raw[2])*3.f;
        float e0 = Bs[0] + tanhf(raw[3])*2.f;
        float e1 = Bs[1] + tanhf(raw[4])*2.f;
        float e2 = Bs[2] + tanhf(raw[5])*2.f;
        float sl0 = fmaxf(expf(e0), 1e-6f);
        float sl1 = fmaxf(expf(e1), 1e-6f);
        float sl2 = fmaxf(expf(e2), 1e-6f);
        float p0 = A[0] + u0*sl0, p1 = A[1] + u1*sl1, p2 = A[2] + u2*sl2;
        float mu0 = R[0]*p0 + R[1]*p1 + R[2]*p2 + T[0];
        float mu1 = R[3]*p0 + R[4]*p1 + R[5]*p2 + T[1];
        float mu2 = R[6]*p0 + R[7]*p1 + R[8]*p2 + T[2];
        float v0 = expf(2.f*e0), v1 = expf(2.f*e1), v2 = expf(2.f*e2);
        float s00 = R[0]*R[0]*v0 + R[1]*R[1]*v1 + R[2]*R[2]*v2;
        float s01 = R[0]*R[3]*v0 + R[1]*R[4]*v1 + R[2]*R[5]*v2;
        float s02 = R[0]*R[6]*v0 + R[1]*R[7]*v1 + R[2]*R[8]*v2;
        float s11 = R[3]*R[3]*v0 + R[4]*R[4]*v1 + R[5]*R[5]*v2;
        float s12 = R[3]*R[6]*v0 + R[4]*R[7]*v1 + R[5]*R[8]*v2;
        float s22 = R[6]*R[6]*v0 + R[7]*R[7]*v1 + R[8]*R[8]*v2;
        float* mud = (side ? kmu : qmu) + (size_t)bn*48 + item*3;
        mud[0]=mu0; mud[1]=mu1; mud[2]=mu2;
        float* sgd = (side ? ksig : qsig) + (size_t)bn*96 + item*6;
        sgd[0]=s00; sgd[1]=s01; sgd[2]=s02; sgd[3]=s11; sgd[4]=s12; sgd[5]=s22;
    }
}

// ---------------- K3: fused attention, one block per (b,i) ----------------
// All z-projection weights live in REGISTERS (wreg[16], 64 VGPRs) so the
// chunk-loop dot phase has zero global memory ops -> no per-q vmcnt drains.
__global__ void __launch_bounds__(256, 3)
k_attn(const float* __restrict__ z, const float* __restrict__ mask,
       const float* __restrict__ rot, const float* __restrict__ trans,
       const float* __restrict__ lin,
       const float* __restrict__ qmu, const float* __restrict__ qsig,
       const float* __restrict__ kmu, const float* __restrict__ ksig,
       const float* __restrict__ vpg, const unsigned int* __restrict__ wc,
       const float* __restrict__ bb, const float* __restrict__ bdz,
       const float* __restrict__ gsc, const float* __restrict__ gbi,
       float* __restrict__ cat) {
    __shared__ float  logits[NH][NN];           // 12 KB
    __shared__ unsigned short zh[24][128];      // 6 KB (f16 z chunk)
    __shared__ __half pzl[NN][36];              // 27.65 KB (pz row, padded stride)
    __shared__ float  qrow[128];
    __shared__ float  qmu_s[48], qsig_s[96];
    __shared__ float  Rm[9], Tv[3];
    __shared__ float  aH[NH], bH[NH];
    __shared__ float  maskI;

    int t  = threadIdx.x;
    int b  = blockIdx.x / NN, i = blockIdx.x % NN;
    int bi = b*NN + i;
    const float* zbase = z + (size_t)bi*NN*NCZ;

    // ---- issue chunk-0 z prefetch first ----
    float4 pre0 = *reinterpret_cast<const float4*>(zbase +    0 + t*4);
    float4 pre1 = *reinterpret_cast<const float4*>(zbase + 1024 + t*4);
    float4 pre2 = *reinterpret_cast<const float4*>(zbase + 2048 + t*4);

    // ---- preload this thread's z-projection weight row into registers ----
    int oc = t % 40, g6 = t / 40;   // 240 workers: oc in [0,40), 6 j-groups of 4
    const unsigned int* wrow = wc + oc*64;
    uint4 wr0  = *reinterpret_cast<const uint4*>(wrow +  0);
    uint4 wr1  = *reinterpret_cast<const uint4*>(wrow +  4);
    uint4 wr2  = *reinterpret_cast<const uint4*>(wrow +  8);
    uint4 wr3  = *reinterpret_cast<const uint4*>(wrow + 12);
    uint4 wr4  = *reinterpret_cast<const uint4*>(wrow + 16);
    uint4 wr5  = *reinterpret_cast<const uint4*>(wrow + 20);
    uint4 wr6  = *reinterpret_cast<const uint4*>(wrow + 24);
    uint4 wr7  = *reinterpret_cast<const uint4*>(wrow + 28);
    uint4 wr8  = *reinterpret_cast<const uint4*>(wrow + 32);
    uint4 wr9  = *reinterpret_cast<const uint4*>(wrow + 36);
    uint4 wr10 = *reinterpret_cast<const uint4*>(wrow + 40);
    uint4 wr11 = *reinterpret_cast<const uint4*>(wrow + 44);
    uint4 wr12 = *reinterpret_cast<const uint4*>(wrow + 48);
    uint4 wr13 = *reinterpret_cast<const uint4*>(wrow + 52);
    uint4 wr14 = *reinterpret_cast<const uint4*>(wrow + 56);
    uint4 wr15 = *reinterpret_cast<const uint4*>(wrow + 60);
    float biasv = (oc < 8) ? bb[oc] : bdz[oc-8];

    // ---- stage per-row scalars ----
    if (t < 128) qrow[t] = lin[(size_t)bi*LINW + t];
    if (t < 48)  qmu_s[t] = qmu[(size_t)bi*48 + t];
    if (t >= 64 && t < 160) qsig_s[t-64] = qsig[(size_t)bi*96 + (t-64)];
    if (t >= 160 && t < 169) Rm[t-160] = rot[bi*9 + (t-160)];
    if (t >= 169 && t < 172) Tv[t-169] = trans[bi*3 + (t-169)];
    if (t >= 176 && t < 184) {
        int h = t-176;
        float x = gsc[h];
        aH[h] = (x > 20.f) ? x : log1pf(expf(x));
        bH[h] = gbi[h];
    }
    if (t == 255) maskI = mask[bi];
    __syncthreads();

    // ---- phase 0: qk + geo NLL + mask + bias for ALL j (init logits) ----
    {
        int h = t >> 5, lane = t & 31;
        float qv[16];
        #pragma unroll
        for (int d = 0; d < 16; ++d) qv[d] = qrow[h*16 + d];
        float qm[6], qs[12];
        #pragma unroll
        for (int e = 0; e < 6; ++e)  qm[e] = qmu_s[h*6 + e];
        #pragma unroll
        for (int e = 0; e < 12; ++e) qs[e] = qsig_s[h*12 + e];
        float ascale = aH[h], hbias = bH[h], mI = maskI;
        for (int jj = 0; jj < 12; ++jj) {
            int j = lane + jj*32;
            size_t jrow = (size_t)(b*NN + j);
            const float* kp = lin + jrow*LINW + 128 + h*NCH;
            float4 k0 = *(const float4*)(kp);
            float4 k1 = *(const float4*)(kp+4);
            float4 k2 = *(const float4*)(kp+8);
            float4 k3 = *(const float4*)(kp+12);
            float qk = qv[0]*k0.x + qv[1]*k0.y + qv[2]*k0.z + qv[3]*k0.w
                     + qv[4]*k1.x + qv[5]*k1.y + qv[6]*k1.z + qv[7]*k1.w
                     + qv[8]*k2.x + qv[9]*k2.y + qv[10]*k2.z + qv[11]*k2.w
                     + qv[12]*k3.x + qv[13]*k3.y + qv[14]*k3.z + qv[15]*k3.w;
            float geo = 0.f;
            #pragma unroll
            for (int g = 0; g < NG; ++g) {
                const float* km = kmu + jrow*48 + h*6 + g*3;
                const float* ks = ksig + jrow*96 + h*12 + g*6;
                float d0 = qm[g*3+0] - km[0];
                float d1 = qm[g*3+1] - km[1];
                float d2 = qm[g*3+2] - km[2];
                float s00 = qs[g*6+0] + ks[0];
                float s01 = qs[g*6+1] + ks[1];
                float s02 = qs[g*6+2] + ks[2];
                float s11 = qs[g*6+3] + ks[3];
                float s12 = qs[g*6+4] + ks[4];
                float s22 = qs[g*6+5] + ks[5];
                float l00 = fmaxf(s00, 1e-8f);
                float i00 = rsqrtf(l00);
                float l10 = s01*i00, l20 = s02*i00;
                float l11 = fmaxf(s11 - l10*l10, 1e-8f);
                float i11 = rsqrtf(l11);
                float l21 = (s12 - l20*l10)*i11;
                float l22 = fmaxf(s22 - l20*l20 - l21*l21, 1e-8f);
                float i22 = rsqrtf(l22);
                float ld = __logf(l00) + __logf(l11) + __logf(l22);
                float y0 = d0*i00;
                float y1 = (d1 - l10*y0)*i11;
                float y2 = (d2 - l20*y0 - l21*y1)*i22;
                geo += -0.5f*(y0*y0 + y1*y1 + y2*y2 + ld);
            }
            float m2 = mI * mask[b*NN + j];
            logits[h][j] = qk*0.25f + ascale*(geo*m2) + hbias + (1.f - m2)*(-100000.f);
        }
    }

    // ---- chunk loop: z-dots, zero global ops in the dot phase ----
    #pragma unroll 1
    for (int ch = 0; ch < 16; ++ch) {
        int j0 = ch*24;
        // regs -> LDS (f16); the only vmcnt wait per chunk happens here.
        {
            int idx = t*4;
            __half2* d0 = reinterpret_cast<__half2*>(&zh[idx>>7][idx&127]);
            d0[0] = __floats2half2_rn(pre0.x, pre0.y);
            d0[1] = __floats2half2_rn(pre0.z, pre0.w);
            int idx1 = idx + 1024;
            __half2* d1 = reinterpret_cast<__half2*>(&zh[idx1>>7][idx1&127]);
            d1[0] = __floats2half2_rn(pre1.x, pre1.y);
            d1[1] = __floats2half2_rn(pre1.z, pre1.w);
            int idx2 = idx + 2048;
            __half2* d2 = reinterpret_cast<__half2*>(&zh[idx2>>7][idx2&127]);
            d2[0] = __floats2half2_rn(pre2.x, pre2.y);
            d2[1] = __floats2half2_rn(pre2.z, pre2.w);
        }
        if (ch < 15) {  // next chunk's prefetch; stays in flight across barrier+dots
            const float* zp = zbase + (size_t)(j0 + 24)*NCZ;
            pre0 = *reinterpret_cast<const float4*>(zp +    0 + t*4);
            pre1 = *reinterpret_cast<const float4*>(zp + 1024 + t*4);
            pre2 = *reinterpret_cast<const float4*>(zp + 2048 + t*4);
        }
        __syncthreads();
        if (t < 240) {
            float a0=0.f, a1=0.f, a2=0.f, a3=0.f;
            int jb = g6*4;
            #define DOTQ(Q, WV)                                                     \
            {   uint4 z0 = *reinterpret_cast<const uint4*>(&zh[jb+0][(Q)*8]);       \
                uint4 z1 = *reinterpret_cast<const uint4*>(&zh[jb+1][(Q)*8]);       \
                uint4 z2 = *reinterpret_cast<const uint4*>(&zh[jb+2][(Q)*8]);       \
                uint4 z3 = *reinterpret_cast<const uint4*>(&zh[jb+3][(Q)*8]);       \
                a0 = fdot2a(z0.x, WV.x, a0); a0 = fdot2a(z0.y, WV.y, a0);           \
                a0 = fdot2a(z0.z, WV.z, a0); a0 = fdot2a(z0.w, WV.w, a0);           \
                a1 = fdot2a(z1.x, WV.x, a1); a1 = fdot2a(z1.y, WV.y, a1);           \
                a1 = fdot2a(z1.z, WV.z, a1); a1 = fdot2a(z1.w, WV.w, a1);           \
                a2 = fdot2a(z2.x, WV.x, a2); a2 = fdot2a(z2.y, WV.y, a2);           \
                a2 = fdot2a(z2.z, WV.z, a2); a2 = fdot2a(z2.w, WV.w, a2);           \
                a3 = fdot2a(z3.x, WV.x, a3); a3 = fdot2a(z3.y, WV.y, a3);           \
                a3 = fdot2a(z3.z, WV.z, a3); a3 = fdot2a(z3.w, WV.w, a3); }
            DOTQ(0,  wr0)  DOTQ(1,  wr1)  DOTQ(2,  wr2)  DOTQ(3,  wr3)
            DOTQ(4,  wr4)  DOTQ(5,  wr5)  DOTQ(6,  wr6)  DOTQ(7,  wr7)
            DOTQ(8,  wr8)  DOTQ(9,  wr9)  DOTQ(10, wr10) DOTQ(11, wr11)
            DOTQ(12, wr12) DOTQ(13, wr13) DOTQ(14, wr14) DOTQ(15, wr15)
            #undef DOTQ
            if (oc < 8) {
                logits[oc][j0+jb+0] += a0 + biasv;
                logits[oc][j0+jb+1] += a1 + biasv;
                logits[oc][j0+jb+2] += a2 + biasv;
                logits[oc][j0+jb+3] += a3 + biasv;
            } else {
                int c4 = oc - 8;
                pzl[j0+jb+0][c4] = __float2half(a0 + biasv);
                pzl[j0+jb+1][c4] = __float2half(a1 + biasv);
                pzl[j0+jb+2][c4] = __float2half(a2 + biasv);
                pzl[j0+jb+3][c4] = __float2half(a3 + biasv);
            }
        }
        __syncthreads();
    }

    // --- softmax per head (32 lanes per head) ---
    int h = t >> 5, lane = t & 31;
    float mx = -3.4e38f;
    #pragma unroll
    for (int jj = 0; jj < 12; ++jj) mx = fmaxf(mx, logits[h][lane + jj*32]);
    #pragma unroll
    for (int m = 16; m >= 1; m >>= 1) mx = fmaxf(mx, __shfl_xor(mx, m, 64));
    float se = 0.f;
    #pragma unroll
    for (int jj = 0; jj < 12; ++jj) {
        int j = lane + jj*32;
        float e = __expf(logits[h][j] - mx);
        logits[h][j] = e;
        se += e;
    }
    #pragma unroll
    for (int m = 16; m >= 1; m >>= 1) se += __shfl_xor(se, m, 64);
    float inv = 1.f / se;

    // --- pass 2: o / opt / opair accumulation ---
    float o[16], op[24], opa[32];
    #pragma unroll
    for (int d = 0; d < 16; ++d) o[d] = 0.f;
    #pragma unroll
    for (int e = 0; e < 24; ++e) op[e] = 0.f;
    #pragma unroll
    for (int c = 0; c < 32; ++c) opa[c] = 0.f;

    for (int jj = 0; jj < 12; ++jj) {
        int j = lane + jj*32;
        float w = logits[h][j] * inv;
        size_t jrow = (size_t)(b*NN + j);
        const float* vp = lin + jrow*LINW + 256 + h*NCH;
        float vv[16];
        *reinterpret_cast<float4*>(&vv[0])  = *(const float4*)(vp);
        *reinterpret_cast<float4*>(&vv[4])  = *(const float4*)(vp+4);
        *reinterpret_cast<float4*>(&vv[8])  = *(const float4*)(vp+8);
        *reinterpret_cast<float4*>(&vv[12]) = *(const float4*)(vp+12);
        #pragma unroll
        for (int d = 0; d < 16; ++d) o[d] = fmaf(w, vv[d], o[d]);
        const float* vg = vpg + jrow*(NH*NP*3) + h*24;
        float gg[24];
        #pragma unroll
        for (int q4 = 0; q4 < 6; ++q4)
            *reinterpret_cast<float4*>(&gg[q4*4]) = *(const float4*)(vg + q4*4);
        #pragma unroll
        for (int e = 0; e < 24; ++e) op[e] = fmaf(w, gg[e], op[e]);
        const __half2* pzp = reinterpret_cast<const __half2*>(&pzl[j][0]);
        #pragma unroll
        for (int c2 = 0; c2 < 16; ++c2) {
            float2 pf = __half22float2(pzp[c2]);
            opa[2*c2]   = fmaf(w, pf.x, opa[2*c2]);
            opa[2*c2+1] = fmaf(w, pf.y, opa[2*c2+1]);
        }
    }
    // butterfly reduce across the 32 lanes of this head
    #pragma unroll
    for (int m = 16; m >= 1; m >>= 1) {
        #pragma unroll
        for (int d = 0; d < 16; ++d) o[d] += __shfl_xor(o[d], m, 64);
        #pragma unroll
        for (int e = 0; e < 24; ++e) op[e] += __shfl_xor(op[e], m, 64);
        #pragma unroll
        for (int c = 0; c < 32; ++c) opa[c] += __shfl_xor(opa[c], m, 64);
    }
    if (lane == 0) {
        float* cp = cat + (size_t)bi*640;
        #pragma unroll
        for (int d = 0; d < 16; ++d) cp[h*16 + d] = o[d];
        #pragma unroll
        for (int p = 0; p < 8; ++p) {
            float x  = op[p*3+0] - Tv[0];
            float y  = op[p*3+1] - Tv[1];
            float zz = op[p*3+2] - Tv[2];
            float l0 = Rm[0]*x + Rm[3]*y + Rm[6]*zz;   // R^T * (opt - trans)
            float l1 = Rm[1]*x + Rm[4]*y + Rm[7]*zz;
            float l2 = Rm[2]*x + Rm[5]*y + Rm[8]*zz;
            cp[128 + h*24 + p*3 + 0] = l0;
            cp[128 + h*24 + p*3 + 1] = l1;
            cp[128 + h*24 + p*3 + 2] = l2;
            cp[320 + h*8 + p] = sqrtf(l0*l0 + l1*l1 + l2*l2 + 1e-8f);
        }
        #pragma unroll
        for (int c = 0; c < 32; ++c) cp[384 + h*32 + c] = opa[c];
    }
}

// ---------------- K4: out = cat @ Wout + bout ----------------
__global__ void k_out(const float* __restrict__ cat, const float* __restrict__ Wout,
                      const float* __restrict__ bout, float* __restrict__ out) {
    __shared__ float cl[4][640];
    int t  = threadIdx.x;
    int r0 = blockIdx.x * 4;
    for (int idx = t; idx < 4*640; idx += 384)
        cl[idx/640][idx%640] = cat[(size_t)(r0 + idx/640)*640 + (idx%640)];
    __syncthreads();
    int col = t;  // 384 threads == 384 cols
    float a0=0.f, a1=0.f, a2=0.f, a3=0.f;
    for (int c = 0; c < 640; ++c) {
        float w = Wout[(size_t)c*NCS + col];
        a0 = fmaf(cl[0][c], w, a0);
        a1 = fmaf(cl[1][c], w, a1);
        a2 = fmaf(cl[2][c], w, a2);
        a3 = fmaf(cl[3][c], w, a3);
    }
    float bv = bout[col];
    out[(size_t)(r0+0)*NCS + col] = a0 + bv;
    out[(size_t)(r0+1)*NCS + col] = a1 + bv;
    out[(size_t)(r0+2)*NCS + col] = a2 + bv;
    out[(size_t)(r0+3)*NCS + col] = a3 + bv;
}

extern "C" void kernel_launch(void* const* d_in, const int* in_sizes, int n_in,
                              void* d_out, int out_size, void* d_ws, size_t ws_size,
                              hipStream_t stream) {
    const float* s    = (const float*)d_in[0];
    const float* z    = (const float*)d_in[1];
    const float* mask = (const float*)d_in[2];
    const float* rot  = (const float*)d_in[3];
    const float* trans= (const float*)d_in[4];
    const float* lm   = (const float*)d_in[5];
    const float* sc   = (const float*)d_in[6];
    const float* Wq   = (const float*)d_in[7];
    const float* Wk   = (const float*)d_in[8];
    const float* Wv   = (const float*)d_in[9];
    const float* Wb   = (const float*)d_in[10];
    const float* bb   = (const float*)d_in[11];
    const float* Wdz  = (const float*)d_in[12];
    const float* bdz  = (const float*)d_in[13];
    const float* Wqg  = (const float*)d_in[14];
    const float* bqg  = (const float*)d_in[15];
    const float* Wkg  = (const float*)d_in[16];
    const float* bkg  = (const float*)d_in[17];
    const float* Wvp  = (const float*)d_in[18];
    const float* bvp  = (const float*)d_in[19];
    const float* gsc  = (const float*)d_in[20];
    const float* gbi  = (const float*)d_in[21];
    const float* Wout = (const float*)d_in[22];
    const float* bout = (const float*)d_in[23];
    float* out = (float*)d_out;

    float* ws   = (float*)d_ws;
    float* lin  = ws;                    // 768*768      = 589824
    float* qmu  = lin  + 589824;         // 768*48       = 36864
    float* qsig = qmu  + 36864;          // 768*96       = 73728
    float* kmu  = qsig + 73728;          // 36864
    float* ksig = kmu  + 36864;          // 73728
    float* vpg  = ksig + 73728;          // 768*192      = 147456
    float* cat  = vpg  + 147456;         // 768*640      = 491520
    unsigned int* wc = (unsigned int*)(cat + 491520);   // 40*64 = 2560 u32

    k_wprep<<<1, 256, 0, stream>>>(Wb, Wdz, wc);
    k_rowlin<<<dim3(192, 3), 256, 0, stream>>>(s, Wq, Wk, Wv, Wqg, bqg, Wkg, bkg,
                                               Wvp, bvp, lin);
    k_geom<<<BN, 64, 0, stream>>>(lin, rot, trans, lm, sc, qmu, qsig, kmu, ksig, vpg);
    k_attn<<<BN, 256, 0, stream>>>(z, mask, rot, trans, lin, qmu, qsig, kmu, ksig,
                                   vpg, wc, bb, bdz, gsc, gbi, cat);
    k_out<<<192, 384, 0, stream>>>(cat, Wout, bout, out);
}

// Round 4
// 180.094 us; speedup vs baseline: 1.9846x; 1.0673x over previous
//
#include <hip/hip_runtime.h>
#include <hip/hip_fp16.h>

// InvariantGaussianAttention, MI355X (gfx950)
// B=2 N=384 CS=384 CZ=128 H=8 CH=16 G=2 P=8 CZ4=32
#define NB   2
#define NN   384
#define NCS  384
#define NCZ  128
#define NH   8
#define NCH  16
#define NG   2
#define NP   8
#define NCZ4 32
#define BN   (NB*NN)   // 768
#define LINW 768       // q(128)|k(128)|v(128)|qg(96)|kg(96)|vp(192)

typedef _Float16 f16x8 __attribute__((ext_vector_type(8)));
typedef float    f32x4 __attribute__((ext_vector_type(4)));

// ---------------- K0: build MFMA B-fragments of [Wb | Wdz | 0pad] (f16) -------------
// wf[nk=n*4+kk][lane][r] = W[c = kk*32 + (lane>>4)*8 + r][col = n*16 + (lane&15)]
__global__ void k_wprep(const float* __restrict__ Wb, const float* __restrict__ Wdz,
                        _Float16* __restrict__ wf) {
    int t = threadIdx.x;
    for (int e = t; e < 12*64*8; e += 256) {
        int r = e & 7, lane = (e >> 3) & 63, nk = e >> 9;
        int n = nk >> 2, kk = nk & 3;
        int c = kk*32 + (lane >> 4)*8 + r;
        int col = n*16 + (lane & 15);
        float w;
        if      (col < 8)  w = Wb[c*NH + col];
        else if (col < 40) w = Wdz[c*NCZ4 + (col-8)];
        else               w = 0.f;
        wf[e] = (_Float16)w;
    }
}

// ---------------- K1: fused row linear  lin = s @ [Wq|Wk|Wv|Wqg|Wkg|Wvp] ----------------
__global__ void k_rowlin(const float* __restrict__ s,
                         const float* __restrict__ Wq, const float* __restrict__ Wk,
                         const float* __restrict__ Wv,
                         const float* __restrict__ Wqg, const float* __restrict__ bqg,
                         const float* __restrict__ Wkg, const float* __restrict__ bkg,
                         const float* __restrict__ Wvp, const float* __restrict__ bvp,
                         float* __restrict__ lin) {
    __shared__ float sl[4][NCS];
    int t  = threadIdx.x;
    int r0 = blockIdx.x * 4;
    for (int idx = t; idx < 4*NCS; idx += 256)
        sl[idx / NCS][idx % NCS] = s[(size_t)(r0 + idx/NCS)*NCS + (idx % NCS)];
    __syncthreads();
    int col = blockIdx.y * 256 + t;
    const float* W; int sw; float bias = 0.f;
    if      (col < 128) { W = Wq  + col;        sw = 128; }
    else if (col < 256) { W = Wk  + (col-128);  sw = 128; }
    else if (col < 384) { W = Wv  + (col-256);  sw = 128; }
    else if (col < 480) { W = Wqg + (col-384);  sw = 96;  bias = bqg[col-384]; }
    else if (col < 576) { W = Wkg + (col-480);  sw = 96;  bias = bkg[col-480]; }
    else                { W = Wvp + (col-576);  sw = 192; bias = bvp[col-576]; }
    float a0=0.f, a1=0.f, a2=0.f, a3=0.f;
    for (int c = 0; c < NCS; ++c) {
        float w = W[(size_t)c*sw];
        a0 = fmaf(sl[0][c], w, a0);
        a1 = fmaf(sl[1][c], w, a1);
        a2 = fmaf(sl[2][c], w, a2);
        a3 = fmaf(sl[3][c], w, a3);
    }
    lin[(size_t)(r0+0)*LINW + col] = a0 + bias;
    lin[(size_t)(r0+1)*LINW + col] = a1 + bias;
    lin[(size_t)(r0+2)*LINW + col] = a2 + bias;
    lin[(size_t)(r0+3)*LINW + col] = a3 + bias;
}

// ---------------- K2: to_global (mu, Sigma) + rotated value points ----------------
__global__ void k_geom(const float* __restrict__ lin, const float* __restrict__ rot,
                       const float* __restrict__ trans, const float* __restrict__ lm,
                       const float* __restrict__ sc,
                       float* __restrict__ qmu, float* __restrict__ qsig,
                       float* __restrict__ kmu, float* __restrict__ ksig,
                       float* __restrict__ vpg) {
    int bn = blockIdx.x, t = threadIdx.x;
    __shared__ float R[9], T[3], A[3], Bs[3];
    if (t < 9) R[t] = rot[bn*9 + t];
    if (t < 3) { T[t] = trans[bn*3+t]; A[t] = lm[bn*3+t]; Bs[t] = sc[bn*3+t]; }
    __syncthreads();
    {   // value points: one per thread (h=t/8, p=t&7)
        int h = t >> 3, p = t & 7;
        const float* vr = lin + (size_t)bn*LINW + 576 + h*24 + p*3;
        float x = vr[0], y = vr[1], z = vr[2];
        float* d = vpg + (size_t)bn*(NH*NP*3) + h*24 + p*3;
        d[0] = R[0]*x + R[1]*y + R[2]*z + T[0];
        d[1] = R[3]*x + R[4]*y + R[5]*z + T[1];
        d[2] = R[6]*x + R[7]*y + R[8]*z + T[2];
    }
    if (t < 32) {
        int side = t >> 4, item = t & 15;      // item = h*2+g
        const float* raw = lin + (size_t)bn*LINW + (side ? 480 : 384) + item*6;
        float u0 = tanhf(raw[0])*3.f, u1 = tanhf(raw[1])*3.f, u2 = tanhf(raw[2])*3.f;
        float e0 = Bs[0] + tanhf(raw[3])*2.f;
        float e1 = Bs[1] + tanhf(raw[4])*2.f;
        float e2 = Bs[2] + tanhf(raw[5])*2.f;
        float sl0 = fmaxf(expf(e0), 1e-6f);
        float sl1 = fmaxf(expf(e1), 1e-6f);
        float sl2 = fmaxf(expf(e2), 1e-6f);
        float p0 = A[0] + u0*sl0, p1 = A[1] + u1*sl1, p2 = A[2] + u2*sl2;
        float mu0 = R[0]*p0 + R[1]*p1 + R[2]*p2 + T[0];
        float mu1 = R[3]*p0 + R[4]*p1 + R[5]*p2 + T[1];
        float mu2 = R[6]*p0 + R[7]*p1 + R[8]*p2 + T[2];
        float v0 = expf(2.f*e0), v1 = expf(2.f*e1), v2 = expf(2.f*e2);
        float s00 = R[0]*R[0]*v0 + R[1]*R[1]*v1 + R[2]*R[2]*v2;
        float s01 = R[0]*R[3]*v0 + R[1]*R[4]*v1 + R[2]*R[5]*v2;
        float s02 = R[0]*R[6]*v0 + R[1]*R[7]*v1 + R[2]*R[8]*v2;
        float s11 = R[3]*R[3]*v0 + R[4]*R[4]*v1 + R[5]*R[5]*v2;
        float s12 = R[3]*R[6]*v0 + R[4]*R[7]*v1 + R[5]*R[8]*v2;
        float s22 = R[6]*R[6]*v0 + R[7]*R[7]*v1 + R[8]*R[8]*v2;
        float* mud = (side ? kmu : qmu) + (size_t)bn*48 + item*3;
        mud[0]=mu0; mud[1]=mu1; mud[2]=mu2;
        float* sgd = (side ? ksig : qsig) + (size_t)bn*96 + item*6;
        sgd[0]=s00; sgd[1]=s01; sgd[2]=s02; sgd[3]=s11; sgd[4]=s12; sgd[5]=s22;
    }
}

// ---------------- K3: fused attention, one block per (b,i), MFMA z-projection ----------------
__global__ void __launch_bounds__(256, 2)
k_attn(const float* __restrict__ z, const float* __restrict__ mask,
       const float* __restrict__ rot, const float* __restrict__ trans,
       const float* __restrict__ lin,
       const float* __restrict__ qmu, const float* __restrict__ qsig,
       const float* __restrict__ kmu, const float* __restrict__ ksig,
       const float* __restrict__ vpg, const _Float16* __restrict__ wf,
       const float* __restrict__ bb, const float* __restrict__ bdz,
       const float* __restrict__ gsc, const float* __restrict__ gbi,
       float* __restrict__ cat) {
    __shared__ __align__(16) _Float16 zh[64*128];  // 16 KB, XOR-swizzled rows
    __shared__ float  logits[NH][NN];              // 12 KB
    __shared__ __half pzl[NN][34];                 // 26.1 KB (stride 17 words: conflict-free)
    __shared__ float  qrow[128];
    __shared__ float  qmu_s[48], qsig_s[96];
    __shared__ float  Rm[9], Tv[3];
    __shared__ float  aH[NH], bH[NH];
    __shared__ float  bias_s[48];
    __shared__ float  maskI;

    int t  = threadIdx.x;
    int lane = t & 63, w = t >> 6;
    int b  = blockIdx.x / NN, i = blockIdx.x % NN;
    int bi = b*NN + i;
    const float* zbase = z + (size_t)bi*NN*NCZ;

    // ---- 2-deep chunk prefetch: chunks 0 and 1 (8 x float4 per thread each) ----
    const float* zrow0 = zbase + (size_t)(t >> 5)*NCZ + (t & 31)*4;
    float4 preA[8], preB[8];
    #pragma unroll
    for (int p = 0; p < 8; ++p) preA[p] = *(const float4*)(zrow0 + (size_t)(p*8)*NCZ);
    #pragma unroll
    for (int p = 0; p < 8; ++p) preB[p] = *(const float4*)(zrow0 + (size_t)(64 + p*8)*NCZ);

    // ---- B-fragments for the 3 N-tiles x 4 K-steps (held whole kernel) ----
    f16x8 bfr[12];
    #pragma unroll
    for (int nk = 0; nk < 12; ++nk)
        bfr[nk] = ((const f16x8*)wf)[nk*64 + lane];

    // ---- stage per-row scalars ----
    if (t < 128) qrow[t] = lin[(size_t)bi*LINW + t];
    if (t < 48)  qmu_s[t] = qmu[(size_t)bi*48 + t];
    if (t < 48)  bias_s[t] = (t < 8) ? bb[t] : ((t < 40) ? bdz[t-8] : 0.f);
    if (t >= 64 && t < 160) qsig_s[t-64] = qsig[(size_t)bi*96 + (t-64)];
    if (t >= 160 && t < 169) Rm[t-160] = rot[bi*9 + (t-160)];
    if (t >= 169 && t < 172) Tv[t-169] = trans[bi*3 + (t-169)];
    if (t >= 176 && t < 184) {
        int h = t-176;
        float x = gsc[h];
        aH[h] = (x > 20.f) ? x : log1pf(expf(x));
        bH[h] = gbi[h];
    }
    if (t == 255) maskI = mask[bi];
    __syncthreads();

    // ---- phase 0: qk + geo NLL + mask + bias for ALL j (init logits) ----
    {
        int h = t >> 5, lnn = t & 31;
        float qv[16];
        #pragma unroll
        for (int d = 0; d < 16; ++d) qv[d] = qrow[h*16 + d];
        float qm[6], qs[12];
        #pragma unroll
        for (int e = 0; e < 6; ++e)  qm[e] = qmu_s[h*6 + e];
        #pragma unroll
        for (int e = 0; e < 12; ++e) qs[e] = qsig_s[h*12 + e];
        float ascale = aH[h], hbias = bH[h], mI = maskI;
        for (int jj = 0; jj < 12; ++jj) {
            int j = lnn + jj*32;
            size_t jrow = (size_t)(b*NN + j);
            const float* kp = lin + jrow*LINW + 128 + h*NCH;
            float4 k0 = *(const float4*)(kp);
            float4 k1 = *(const float4*)(kp+4);
            float4 k2 = *(const float4*)(kp+8);
            float4 k3 = *(const float4*)(kp+12);
            float qk = qv[0]*k0.x + qv[1]*k0.y + qv[2]*k0.z + qv[3]*k0.w
                     + qv[4]*k1.x + qv[5]*k1.y + qv[6]*k1.z + qv[7]*k1.w
                     + qv[8]*k2.x + qv[9]*k2.y + qv[10]*k2.z + qv[11]*k2.w
                     + qv[12]*k3.x + qv[13]*k3.y + qv[14]*k3.z + qv[15]*k3.w;
            float geo = 0.f;
            #pragma unroll
            for (int g = 0; g < NG; ++g) {
                const float* km = kmu + jrow*48 + h*6 + g*3;
                const float* ks = ksig + jrow*96 + h*12 + g*6;
                float d0 = qm[g*3+0] - km[0];
                float d1 = qm[g*3+1] - km[1];
                float d2 = qm[g*3+2] - km[2];
                float s00 = qs[g*6+0] + ks[0];
                float s01 = qs[g*6+1] + ks[1];
                float s02 = qs[g*6+2] + ks[2];
                float s11 = qs[g*6+3] + ks[3];
                float s12 = qs[g*6+4] + ks[4];
                float s22 = qs[g*6+5] + ks[5];
                float l00 = fmaxf(s00, 1e-8f);
                float i00 = rsqrtf(l00);
                float l10 = s01*i00, l20 = s02*i00;
                float l11 = fmaxf(s11 - l10*l10, 1e-8f);
                float i11 = rsqrtf(l11);
                float l21 = (s12 - l20*l10)*i11;
                float l22 = fmaxf(s22 - l20*l20 - l21*l21, 1e-8f);
                float i22 = rsqrtf(l22);
                float ld = __logf(l00) + __logf(l11) + __logf(l22);
                float y0 = d0*i00;
                float y1 = (d1 - l10*y0)*i11;
                float y2 = (d2 - l20*y0 - l21*y1)*i22;
                geo += -0.5f*(y0*y0 + y1*y1 + y2*y2 + ld);
            }
            float m2 = mI * mask[b*NN + j];
            logits[h][j] = qk*0.25f + ascale*(geo*m2) + hbias + (1.f - m2)*(-100000.f);
        }
    }

    // ---- chunk loop: 6 chunks x 64 j rows; stage f16 -> 12 MFMA/wave -> scatter ----
    // staging write: thread t, rep p: row = p*8 + (t>>5), f16 col pair base (t&31)*4
    int srow0 = t >> 5;                 // 0..7
    int scb   = (t & 31) * 8;           // byte base within 256B row
    int sswz  = (srow0 & 7) << 4;       // XOR key (row&7 is p-invariant)
    int arow  = w*16 + (lane & 15);
    int abase = arow*256 + ((lane >> 4) << 4);
    int akey  = (lane & 7) << 4;
    int ccol  = lane & 15;
    int cjl   = w*16 + (lane >> 4)*4;   // local j base of this lane's C rows

#define CHUNK_BODY(CH, PRE)                                                          \
    {                                                                                \
        /* regs -> zh (f16, swizzled); vmcnt wait lands here */                      \
        _Pragma("unroll")                                                            \
        for (int p = 0; p < 8; ++p) {                                                \
            union { _Float16 h[4]; unsigned long long u; } pk;                       \
            pk.h[0] = (_Float16)PRE[p].x; pk.h[1] = (_Float16)PRE[p].y;              \
            pk.h[2] = (_Float16)PRE[p].z; pk.h[3] = (_Float16)PRE[p].w;              \
            *(unsigned long long*)((char*)zh + (p*8 + srow0)*256 + (scb ^ sswz)) = pk.u; \
        }                                                                            \
        if ((CH) + 2 < 6) {   /* issue chunk CH+2 loads; fly across barriers */      \
            const float* src = zbase + (size_t)((CH+2)*64)*NCZ + (size_t)(t>>5)*NCZ  \
                               + (t & 31)*4;                                         \
            _Pragma("unroll")                                                        \
            for (int p = 0; p < 8; ++p)                                              \
                PRE[p] = *(const float4*)(src + (size_t)(p*8)*NCZ);                  \
        }                                                                            \
        __syncthreads();                                                             \
        {                                                                            \
            f16x8 af0 = *(const f16x8*)((const char*)zh + ((abase +   0) ^ akey));   \
            f16x8 af1 = *(const f16x8*)((const char*)zh + ((abase +  64) ^ akey));   \
            f16x8 af2 = *(const f16x8*)((const char*)zh + ((abase + 128) ^ akey));   \
            f16x8 af3 = *(const f16x8*)((const char*)zh + ((abase + 192) ^ akey));   \
            f32x4 ac0 = {0.f,0.f,0.f,0.f}, ac1 = ac0, ac2 = ac0;                     \
            ac0 = __builtin_amdgcn_mfma_f32_16x16x32_f16(af0, bfr[0], ac0, 0,0,0);   \
            ac1 = __builtin_amdgcn_mfma_f32_16x16x32_f16(af0, bfr[4], ac1, 0,0,0);   \
            ac2 = __builtin_amdgcn_mfma_f32_16x16x32_f16(af0, bfr[8], ac2, 0,0,0);   \
            ac0 = __builtin_amdgcn_mfma_f32_16x16x32_f16(af1, bfr[1], ac0, 0,0,0);   \
            ac1 = __builtin_amdgcn_mfma_f32_16x16x32_f16(af1, bfr[5], ac1, 0,0,0);   \
            ac2 = __builtin_amdgcn_mfma_f32_16x16x32_f16(af1, bfr[9], ac2, 0,0,0);   \
            ac0 = __builtin_amdgcn_mfma_f32_16x16x32_f16(af2, bfr[2], ac0, 0,0,0);   \
            ac1 = __builtin_amdgcn_mfma_f32_16x16x32_f16(af2, bfr[6], ac1, 0,0,0);   \
            ac2 = __builtin_amdgcn_mfma_f32_16x16x32_f16(af2, bfr[10], ac2, 0,0,0);  \
            ac0 = __builtin_amdgcn_mfma_f32_16x16x32_f16(af3, bfr[3], ac0, 0,0,0);   \
            ac1 = __builtin_amdgcn_mfma_f32_16x16x32_f16(af3, bfr[7], ac1, 0,0,0);   \
            ac2 = __builtin_amdgcn_mfma_f32_16x16x32_f16(af3, bfr[11], ac2, 0,0,0);  \
            int jg = (CH)*64 + cjl;                                                  \
            _Pragma("unroll")                                                        \
            for (int r = 0; r < 4; ++r) {                                            \
                int j = jg + r;                                                      \
                float v0 = ac0[r] + bias_s[ccol];                                    \
                if (ccol < 8) logits[ccol][j] += v0;                                 \
                else          pzl[j][ccol-8] = __float2half(v0);                     \
                pzl[j][ccol+8] = __float2half(ac1[r] + bias_s[16+ccol]);             \
                if (ccol < 8)                                                        \
                    pzl[j][ccol+24] = __float2half(ac2[r] + bias_s[32+ccol]);        \
            }                                                                        \
        }                                                                            \
        __syncthreads();                                                             \
    }

    CHUNK_BODY(0, preA)
    CHUNK_BODY(1, preB)
    CHUNK_BODY(2, preA)
    CHUNK_BODY(3, preB)
    CHUNK_BODY(4, preA)
    CHUNK_BODY(5, preB)
#undef CHUNK_BODY

    // --- softmax per head (32 lanes per head) ---
    int h = t >> 5, lnn = t & 31;
    float mx = -3.4e38f;
    #pragma unroll
    for (int jj = 0; jj < 12; ++jj) mx = fmaxf(mx, logits[h][lnn + jj*32]);
    #pragma unroll
    for (int m = 16; m >= 1; m >>= 1) mx = fmaxf(mx, __shfl_xor(mx, m, 64));
    float se = 0.f;
    #pragma unroll
    for (int jj = 0; jj < 12; ++jj) {
        int j = lnn + jj*32;
        float e = __expf(logits[h][j] - mx);
        logits[h][j] = e;
        se += e;
    }
    #pragma unroll
    for (int m = 16; m >= 1; m >>= 1) se += __shfl_xor(se, m, 64);
    float inv = 1.f / se;

    // --- pass 2: o / opt / opair accumulation ---
    float o[16], op[24], opa[32];
    #pragma unroll
    for (int d = 0; d < 16; ++d) o[d] = 0.f;
    #pragma unroll
    for (int e = 0; e < 24; ++e) op[e] = 0.f;
    #pragma unroll
    for (int c = 0; c < 32; ++c) opa[c] = 0.f;

    for (int jj = 0; jj < 12; ++jj) {
        int j = lnn + jj*32;
        float wgt = logits[h][j] * inv;
        size_t jrow = (size_t)(b*NN + j);
        const float* vp = lin + jrow*LINW + 256 + h*NCH;
        float vv[16];
        *reinterpret_cast<float4*>(&vv[0])  = *(const float4*)(vp);
        *reinterpret_cast<float4*>(&vv[4])  = *(const float4*)(vp+4);
        *reinterpret_cast<float4*>(&vv[8])  = *(const float4*)(vp+8);
        *reinterpret_cast<float4*>(&vv[12]) = *(const float4*)(vp+12);
        #pragma unroll
        for (int d = 0; d < 16; ++d) o[d] = fmaf(wgt, vv[d], o[d]);
        const float* vg = vpg + jrow*(NH*NP*3) + h*24;
        float gg[24];
        #pragma unroll
        for (int q4 = 0; q4 < 6; ++q4)
            *reinterpret_cast<float4*>(&gg[q4*4]) = *(const float4*)(vg + q4*4);
        #pragma unroll
        for (int e = 0; e < 24; ++e) op[e] = fmaf(wgt, gg[e], op[e]);
        const __half2* pzp = reinterpret_cast<const __half2*>(&pzl[j][0]);
        #pragma unroll
        for (int c2 = 0; c2 < 16; ++c2) {
            float2 pf = __half22float2(pzp[c2]);
            opa[2*c2]   = fmaf(wgt, pf.x, opa[2*c2]);
            opa[2*c2+1] = fmaf(wgt, pf.y, opa[2*c2+1]);
        }
    }
    // butterfly reduce across the 32 lanes of this head
    #pragma unroll
    for (int m = 16; m >= 1; m >>= 1) {
        #pragma unroll
        for (int d = 0; d < 16; ++d) o[d] += __shfl_xor(o[d], m, 64);
        #pragma unroll
        for (int e = 0; e < 24; ++e) op[e] += __shfl_xor(op[e], m, 64);
        #pragma unroll
        for (int c = 0; c < 32; ++c) opa[c] += __shfl_xor(opa[c], m, 64);
    }
    if (lnn == 0) {
        float* cp = cat + (size_t)bi*640;
        #pragma unroll
        for (int d = 0; d < 16; ++d) cp[h*16 + d] = o[d];
        #pragma unroll
        for (int p = 0; p < 8; ++p) {
            float x  = op[p*3+0] - Tv[0];
            float y  = op[p*3+1] - Tv[1];
            float zz = op[p*3+2] - Tv[2];
            float l0 = Rm[0]*x + Rm[3]*y + Rm[6]*zz;   // R^T * (opt - trans)
            float l1 = Rm[1]*x + Rm[4]*y + Rm[7]*zz;
            float l2 = Rm[2]*x + Rm[5]*y + Rm[8]*zz;
            cp[128 + h*24 + p*3 + 0] = l0;
            cp[128 + h*24 + p*3 + 1] = l1;
            cp[128 + h*24 + p*3 + 2] = l2;
            cp[320 + h*8 + p] = sqrtf(l0*l0 + l1*l1 + l2*l2 + 1e-8f);
        }
        #pragma unroll
        for (int c = 0; c < 32; ++c) cp[384 + h*32 + c] = opa[c];
    }
}

// ---------------- K4: out = cat @ Wout + bout ----------------
__global__ void k_out(const float* __restrict__ cat, const float* __restrict__ Wout,
                      const float* __restrict__ bout, float* __restrict__ out) {
    __shared__ float cl[4][640];
    int t  = threadIdx.x;
    int r0 = blockIdx.x * 4;
    for (int idx = t; idx < 4*640; idx += 384)
        cl[idx/640][idx%640] = cat[(size_t)(r0 + idx/640)*640 + (idx%640)];
    __syncthreads();
    int col = t;  // 384 threads == 384 cols
    float a0=0.f, a1=0.f, a2=0.f, a3=0.f;
    for (int c = 0; c < 640; ++c) {
        float w = Wout[(size_t)c*NCS + col];
        a0 = fmaf(cl[0][c], w, a0);
        a1 = fmaf(cl[1][c], w, a1);
        a2 = fmaf(cl[2][c], w, a2);
        a3 = fmaf(cl[3][c], w, a3);
    }
    float bv = bout[col];
    out[(size_t)(r0+0)*NCS + col] = a0 + bv;
    out[(size_t)(r0+1)*NCS + col] = a1 + bv;
    out[(size_t)(r0+2)*NCS + col] = a2 + bv;
    out[(size_t)(r0+3)*NCS + col] = a3 + bv;
}

extern "C" void kernel_launch(void* const* d_in, const int* in_sizes, int n_in,
                              void* d_out, int out_size, void* d_ws, size_t ws_size,
                              hipStream_t stream) {
    const float* s    = (const float*)d_in[0];
    const float* z    = (const float*)d_in[1];
    const float* mask = (const float*)d_in[2];
    const float* rot  = (const float*)d_in[3];
    const float* trans= (const float*)d_in[4];
    const float* lm   = (const float*)d_in[5];
    const float* sc   = (const float*)d_in[6];
    const float* Wq   = (const float*)d_in[7];
    const float* Wk   = (const float*)d_in[8];
    const float* Wv   = (const float*)d_in[9];
    const float* Wb   = (const float*)d_in[10];
    const float* bb   = (const float*)d_in[11];
    const float* Wdz  = (const float*)d_in[12];
    const float* bdz  = (const float*)d_in[13];
    const float* Wqg  = (const float*)d_in[14];
    const float* bqg  = (const float*)d_in[15];
    const float* Wkg  = (const float*)d_in[16];
    const float* bkg  = (const float*)d_in[17];
    const float* Wvp  = (const float*)d_in[18];
    const float* bvp  = (const float*)d_in[19];
    const float* gsc  = (const float*)d_in[20];
    const float* gbi  = (const float*)d_in[21];
    const float* Wout = (const float*)d_in[22];
    const float* bout = (const float*)d_in[23];
    float* out = (float*)d_out;

    float* ws   = (float*)d_ws;
    float* lin  = ws;                    // 768*768      = 589824
    float* qmu  = lin  + 589824;         // 768*48       = 36864
    float* qsig = qmu  + 36864;          // 768*96       = 73728
    float* kmu  = qsig + 73728;          // 36864
    float* ksig = kmu  + 36864;          // 73728
    float* vpg  = ksig + 73728;          // 768*192      = 147456
    float* cat  = vpg  + 147456;         // 768*640      = 491520
    _Float16* wf = (_Float16*)(cat + 491520);   // 12*64*8 = 6144 f16

    k_wprep<<<1, 256, 0, stream>>>(Wb, Wdz, wf);
    k_rowlin<<<dim3(192, 3), 256, 0, stream>>>(s, Wq, Wk, Wv, Wqg, bqg, Wkg, bkg,
                                               Wvp, bvp, lin);
    k_geom<<<BN, 64, 0, stream>>>(lin, rot, trans, lm, sc, qmu, qsig, kmu, ksig, vpg);
    k_attn<<<BN, 256, 0, stream>>>(z, mask, rot, trans, lin, qmu, qsig, kmu, ksig,
                                   vpg, wf, bb, bdz, gsc, gbi, cat);
    k_out<<<192, 384, 0, stream>>>(cat, Wout, bout, out);
}

// Round 5
// 158.540 us; speedup vs baseline: 2.2544x; 1.1360x over previous
//
#include <hip/hip_runtime.h>
#include <hip/hip_fp16.h>

// InvariantGaussianAttention, MI355X (gfx950)
// B=2 N=384 CS=384 CZ=128 H=8 CH=16 G=2 P=8 CZ4=32
#define NB   2
#define NN   384
#define NCS  384
#define NCZ  128
#define NH   8
#define NCH  16
#define NG   2
#define NP   8
#define NCZ4 32
#define BN   (NB*NN)   // 768
#define LINW 768       // q(128)|k(128)|v(128)|qg(96)|kg(96)|vp(192)

typedef _Float16 f16x8 __attribute__((ext_vector_type(8)));
typedef float    f32x4 __attribute__((ext_vector_type(4)));

// ---------------- K0: build MFMA B-fragments of [Wb | Wdz | 0pad] (f16) -------------
// wf[nk=n*4+kk][lane][r] = W[c = kk*32 + (lane>>4)*8 + r][col = n*16 + (lane&15)]
__global__ void k_wprep(const float* __restrict__ Wb, const float* __restrict__ Wdz,
                        _Float16* __restrict__ wf) {
    int t = threadIdx.x;
    for (int e = t; e < 12*64*8; e += 256) {
        int r = e & 7, lane = (e >> 3) & 63, nk = e >> 9;
        int n = nk >> 2, kk = nk & 3;
        int c = kk*32 + (lane >> 4)*8 + r;
        int col = n*16 + (lane & 15);
        float w;
        if      (col < 8)  w = Wb[c*NH + col];
        else if (col < 40) w = Wdz[c*NCZ4 + (col-8)];
        else               w = 0.f;
        wf[e] = (_Float16)w;
    }
}

// ---------------- K1: fused row linear; also emits kT / vT panels ----------------
__global__ void k_rowlin(const float* __restrict__ s,
                         const float* __restrict__ Wq, const float* __restrict__ Wk,
                         const float* __restrict__ Wv,
                         const float* __restrict__ Wqg, const float* __restrict__ bqg,
                         const float* __restrict__ Wkg, const float* __restrict__ bkg,
                         const float* __restrict__ Wvp, const float* __restrict__ bvp,
                         float* __restrict__ lin,
                         float* __restrict__ kT, float* __restrict__ vT) {
    __shared__ float sl[4][NCS];
    int t  = threadIdx.x;
    int r0 = blockIdx.x * 4;
    for (int idx = t; idx < 4*NCS; idx += 256)
        sl[idx / NCS][idx % NCS] = s[(size_t)(r0 + idx/NCS)*NCS + (idx % NCS)];
    __syncthreads();
    int col = blockIdx.y * 256 + t;
    const float* W; int sw; float bias = 0.f;
    if      (col < 128) { W = Wq  + col;        sw = 128; }
    else if (col < 256) { W = Wk  + (col-128);  sw = 128; }
    else if (col < 384) { W = Wv  + (col-256);  sw = 128; }
    else if (col < 480) { W = Wqg + (col-384);  sw = 96;  bias = bqg[col-384]; }
    else if (col < 576) { W = Wkg + (col-480);  sw = 96;  bias = bkg[col-480]; }
    else                { W = Wvp + (col-576);  sw = 192; bias = bvp[col-576]; }
    float a0=0.f, a1=0.f, a2=0.f, a3=0.f;
    for (int c = 0; c < NCS; ++c) {
        float w = W[(size_t)c*sw];
        a0 = fmaf(sl[0][c], w, a0);
        a1 = fmaf(sl[1][c], w, a1);
        a2 = fmaf(sl[2][c], w, a2);
        a3 = fmaf(sl[3][c], w, a3);
    }
    lin[(size_t)(r0+0)*LINW + col] = a0 + bias;
    lin[(size_t)(r0+1)*LINW + col] = a1 + bias;
    lin[(size_t)(r0+2)*LINW + col] = a2 + bias;
    lin[(size_t)(r0+3)*LINW + col] = a3 + bias;
    if (col >= 128 && col < 384) {   // j-major panels for k_attn (no bias here)
        f32x4 v4; v4[0]=a0; v4[1]=a1; v4[2]=a2; v4[3]=a3;
        float* dst = (col < 256) ? (kT + (size_t)(col-128)*BN + r0)
                                 : (vT + (size_t)(col-256)*BN + r0);
        *(f32x4*)dst = v4;
    }
}

// ---------------- K2: to_global; k-side + value points written j-major ----------------
__global__ void k_geom(const float* __restrict__ lin, const float* __restrict__ rot,
                       const float* __restrict__ trans, const float* __restrict__ lm,
                       const float* __restrict__ sc,
                       float* __restrict__ qmu, float* __restrict__ qsig,
                       float* __restrict__ kmuT, float* __restrict__ ksigT,
                       float* __restrict__ vpgT) {
    int bn = blockIdx.x, t = threadIdx.x;
    __shared__ float R[9], T[3], A[3], Bs[3];
    if (t < 9) R[t] = rot[bn*9 + t];
    if (t < 3) { T[t] = trans[bn*3+t]; A[t] = lm[bn*3+t]; Bs[t] = sc[bn*3+t]; }
    __syncthreads();
    {   // value points: one per thread (h=t/8, p=t&7), j-major out
        int h = t >> 3, p = t & 7;
        const float* vr = lin + (size_t)bn*LINW + 576 + h*24 + p*3;
        float x = vr[0], y = vr[1], z = vr[2];
        int e = h*24 + p*3;
        vpgT[(size_t)(e+0)*BN + bn] = R[0]*x + R[1]*y + R[2]*z + T[0];
        vpgT[(size_t)(e+1)*BN + bn] = R[3]*x + R[4]*y + R[5]*z + T[1];
        vpgT[(size_t)(e+2)*BN + bn] = R[6]*x + R[7]*y + R[8]*z + T[2];
    }
    if (t < 32) {
        int side = t >> 4, item = t & 15;      // item = h*2+g
        const float* raw = lin + (size_t)bn*LINW + (side ? 480 : 384) + item*6;
        float u0 = tanhf(raw[0])*3.f, u1 = tanhf(raw[1])*3.f, u2 = tanhf(raw[2])*3.f;
        float e0 = Bs[0] + tanhf(raw[3])*2.f;
        float e1 = Bs[1] + tanhf(raw[4])*2.f;
        float e2 = Bs[2] + tanhf(raw[5])*2.f;
        float sl0 = fmaxf(expf(e0), 1e-6f);
        float sl1 = fmaxf(expf(e1), 1e-6f);
        float sl2 = fmaxf(expf(e2), 1e-6f);
        float p0 = A[0] + u0*sl0, p1 = A[1] + u1*sl1, p2 = A[2] + u2*sl2;
        float mu0 = R[0]*p0 + R[1]*p1 + R[2]*p2 + T[0];
        float mu1 = R[3]*p0 + R[4]*p1 + R[5]*p2 + T[1];
        float mu2 = R[6]*p0 + R[7]*p1 + R[8]*p2 + T[2];
        float v0 = expf(2.f*e0), v1 = expf(2.f*e1), v2 = expf(2.f*e2);
        float s00 = R[0]*R[0]*v0 + R[1]*R[1]*v1 + R[2]*R[2]*v2;
        float s01 = R[0]*R[3]*v0 + R[1]*R[4]*v1 + R[2]*R[5]*v2;
        float s02 = R[0]*R[6]*v0 + R[1]*R[7]*v1 + R[2]*R[8]*v2;
        float s11 = R[3]*R[3]*v0 + R[4]*R[4]*v1 + R[5]*R[5]*v2;
        float s12 = R[3]*R[6]*v0 + R[4]*R[7]*v1 + R[5]*R[8]*v2;
        float s22 = R[6]*R[6]*v0 + R[7]*R[7]*v1 + R[8]*R[8]*v2;
        if (side) {   // k-side: j-major
            kmuT[(size_t)(item*3+0)*BN + bn] = mu0;
            kmuT[(size_t)(item*3+1)*BN + bn] = mu1;
            kmuT[(size_t)(item*3+2)*BN + bn] = mu2;
            ksigT[(size_t)(item*6+0)*BN + bn] = s00;
            ksigT[(size_t)(item*6+1)*BN + bn] = s01;
            ksigT[(size_t)(item*6+2)*BN + bn] = s02;
            ksigT[(size_t)(item*6+3)*BN + bn] = s11;
            ksigT[(size_t)(item*6+4)*BN + bn] = s12;
            ksigT[(size_t)(item*6+5)*BN + bn] = s22;
        } else {      // q-side: row-major (per-block broadcast read)
            float* mud = qmu + (size_t)bn*48 + item*3;
            mud[0]=mu0; mud[1]=mu1; mud[2]=mu2;
            float* sgd = qsig + (size_t)bn*96 + item*6;
            sgd[0]=s00; sgd[1]=s01; sgd[2]=s02; sgd[3]=s11; sgd[4]=s12; sgd[5]=s22;
        }
    }
}

// ---------------- K3: fused attention, one block per (b,i) ----------------
__global__ void __launch_bounds__(256, 2)
k_attn(const float* __restrict__ z, const float* __restrict__ mask,
       const float* __restrict__ rot, const float* __restrict__ trans,
       const float* __restrict__ lin,
       const float* __restrict__ qmu, const float* __restrict__ qsig,
       const float* __restrict__ kmuT, const float* __restrict__ ksigT,
       const float* __restrict__ kT, const float* __restrict__ vT,
       const float* __restrict__ vpgT, const _Float16* __restrict__ wf,
       const float* __restrict__ bb, const float* __restrict__ bdz,
       const float* __restrict__ gsc, const float* __restrict__ gbi,
       float* __restrict__ cat) {
    __shared__ __align__(16) _Float16 zh[64*128];  // 16 KB, XOR-swizzled rows
    __shared__ float  logits[NH][NN];              // 12 KB
    __shared__ __half pzl[NN][34];                 // 26.1 KB (17-dword stride: conflict-free)
    __shared__ float  qrow[128];
    __shared__ float  qmu_s[48], qsig_s[96];
    __shared__ float  Rm[9], Tv[3];
    __shared__ float  aH[NH], bH[NH];
    __shared__ float  bias_s[48];
    __shared__ float  maskI;

    int t  = threadIdx.x;
    int lane = t & 63, w = t >> 6;
    int b  = blockIdx.x / NN, i = blockIdx.x % NN;
    int bi = b*NN + i;
    const float* zbase = z + (size_t)bi*NN*NCZ;
    const size_t boff = (size_t)b*NN;

    // ---- 2-deep chunk prefetch: chunks 0 and 1 (8 x float4 per thread each) ----
    const float* zrow0 = zbase + (size_t)(t >> 5)*NCZ + (t & 31)*4;
    float4 preA[8], preB[8];
    #pragma unroll
    for (int p = 0; p < 8; ++p) preA[p] = *(const float4*)(zrow0 + (size_t)(p*8)*NCZ);
    #pragma unroll
    for (int p = 0; p < 8; ++p) preB[p] = *(const float4*)(zrow0 + (size_t)(64 + p*8)*NCZ);

    // ---- stage per-row scalars ----
    if (t < 128) qrow[t] = lin[(size_t)bi*LINW + t];
    if (t < 48)  qmu_s[t] = qmu[(size_t)bi*48 + t];
    if (t < 48)  bias_s[t] = (t < 8) ? bb[t] : ((t < 40) ? bdz[t-8] : 0.f);
    if (t >= 64 && t < 160) qsig_s[t-64] = qsig[(size_t)bi*96 + (t-64)];
    if (t >= 160 && t < 169) Rm[t-160] = rot[bi*9 + (t-160)];
    if (t >= 169 && t < 172) Tv[t-169] = trans[bi*3 + (t-169)];
    if (t >= 176 && t < 184) {
        int h = t-176;
        float x = gsc[h];
        aH[h] = (x > 20.f) ? x : log1pf(expf(x));
        bH[h] = gbi[h];
    }
    if (t == 255) maskI = mask[bi];
    __syncthreads();

    // ---- phase 0: qk + geo NLL + mask + bias; j-quad mapping, all loads coalesced ----
    {
        int h = t >> 5, lnn = t & 31;
        float qv[16];
        #pragma unroll
        for (int d = 0; d < 16; ++d) qv[d] = qrow[h*16 + d];
        float qm[6], qs[12];
        #pragma unroll
        for (int e = 0; e < 6; ++e)  qm[e] = qmu_s[h*6 + e];
        #pragma unroll
        for (int e = 0; e < 12; ++e) qs[e] = qsig_s[h*12 + e];
        float ascale = aH[h], hbias = bH[h], mI = maskI;
        #pragma unroll 1
        for (int jj = 0; jj < 3; ++jj) {
            int j4 = jj*128 + lnn*4;
            const float* kp = kT + (size_t)(h*16)*BN + boff + j4;
            f32x4 qk = {0.f,0.f,0.f,0.f};
            #pragma unroll
            for (int d = 0; d < 16; ++d) {
                f32x4 kv = *(const f32x4*)(kp + (size_t)d*BN);
                #pragma unroll
                for (int r = 0; r < 4; ++r) qk[r] = fmaf(qv[d], kv[r], qk[r]);
            }
            f32x4 geo = {0.f,0.f,0.f,0.f};
            #pragma unroll
            for (int g = 0; g < NG; ++g) {
                const float* kmb = kmuT + (size_t)((h*2+g)*3)*BN + boff + j4;
                f32x4 km0 = *(const f32x4*)(kmb);
                f32x4 km1 = *(const f32x4*)(kmb + BN);
                f32x4 km2 = *(const f32x4*)(kmb + 2*BN);
                const float* ksb = ksigT + (size_t)((h*2+g)*6)*BN + boff + j4;
                f32x4 ks0 = *(const f32x4*)(ksb);
                f32x4 ks1 = *(const f32x4*)(ksb + BN);
                f32x4 ks2 = *(const f32x4*)(ksb + 2*BN);
                f32x4 ks3 = *(const f32x4*)(ksb + 3*BN);
                f32x4 ks4 = *(const f32x4*)(ksb + 4*BN);
                f32x4 ks5 = *(const f32x4*)(ksb + 5*BN);
                #pragma unroll
                for (int r = 0; r < 4; ++r) {
                    float d0 = qm[g*3+0] - km0[r];
                    float d1 = qm[g*3+1] - km1[r];
                    float d2 = qm[g*3+2] - km2[r];
                    float s00 = qs[g*6+0] + ks0[r];
                    float s01 = qs[g*6+1] + ks1[r];
                    float s02 = qs[g*6+2] + ks2[r];
                    float s11 = qs[g*6+3] + ks3[r];
                    float s12 = qs[g*6+4] + ks4[r];
                    float s22 = qs[g*6+5] + ks5[r];
                    float l00 = fmaxf(s00, 1e-8f);
                    float i00 = rsqrtf(l00);
                    float l10 = s01*i00, l20 = s02*i00;
                    float l11 = fmaxf(s11 - l10*l10, 1e-8f);
                    float i11 = rsqrtf(l11);
                    float l21 = (s12 - l20*l10)*i11;
                    float l22 = fmaxf(s22 - l20*l20 - l21*l21, 1e-8f);
                    float i22 = rsqrtf(l22);
                    float ld = __logf(l00) + __logf(l11) + __logf(l22);
                    float y0 = d0*i00;
                    float y1 = (d1 - l10*y0)*i11;
                    float y2 = (d2 - l20*y0 - l21*y1)*i22;
                    geo[r] += -0.5f*(y0*y0 + y1*y1 + y2*y2 + ld);
                }
            }
            f32x4 mv = *(const f32x4*)(mask + boff + j4);
            f32x4 lg;
            #pragma unroll
            for (int r = 0; r < 4; ++r) {
                float m2 = mI * mv[r];
                lg[r] = qk[r]*0.25f + ascale*(geo[r]*m2) + hbias + (1.f - m2)*(-100000.f);
            }
            *(f32x4*)&logits[h][j4] = lg;
        }
    }

    // ---- B-fragments (loaded after phase 0 to cap VGPR pressure) ----
    f16x8 bfr[12];
    #pragma unroll
    for (int nk = 0; nk < 12; ++nk)
        bfr[nk] = ((const f16x8*)wf)[nk*64 + lane];

    // ---- chunk loop: 6 chunks x 64 j rows; stage f16 -> 12 MFMA/wave -> scatter ----
    int srow0 = t >> 5;                 // 0..7
    int scb   = (t & 31) * 8;           // byte base within 256B row
    int sswz  = (srow0 & 7) << 4;       // XOR key (row&7 is p-invariant)
    int arow  = w*16 + (lane & 15);
    int abase = arow*256 + ((lane >> 4) << 4);
    int akey  = (lane & 7) << 4;
    int ccol  = lane & 15;
    int cjl   = w*16 + (lane >> 4)*4;   // local j base of this lane's C rows

#define CHUNK_BODY(CH, PRE)                                                          \
    {                                                                                \
        _Pragma("unroll")                                                            \
        for (int p = 0; p < 8; ++p) {                                                \
            union { _Float16 h[4]; unsigned long long u; } pk;                       \
            pk.h[0] = (_Float16)PRE[p].x; pk.h[1] = (_Float16)PRE[p].y;              \
            pk.h[2] = (_Float16)PRE[p].z; pk.h[3] = (_Float16)PRE[p].w;              \
            *(unsigned long long*)((char*)zh + (p*8 + srow0)*256 + (scb ^ sswz)) = pk.u; \
        }                                                                            \
        if ((CH) + 2 < 6) {                                                          \
            const float* src = zbase + (size_t)((CH+2)*64)*NCZ + (size_t)(t>>5)*NCZ  \
                               + (t & 31)*4;                                         \
            _Pragma("unroll")                                                        \
            for (int p = 0; p < 8; ++p)                                              \
                PRE[p] = *(const float4*)(src + (size_t)(p*8)*NCZ);                  \
        }                                                                            \
        __syncthreads();                                                             \
        {                                                                            \
            f16x8 af0 = *(const f16x8*)((const char*)zh + ((abase +   0) ^ akey));   \
            f16x8 af1 = *(const f16x8*)((const char*)zh + ((abase +  64) ^ akey));   \
            f16x8 af2 = *(const f16x8*)((const char*)zh + ((abase + 128) ^ akey));   \
            f16x8 af3 = *(const f16x8*)((const char*)zh + ((abase + 192) ^ akey));   \
            f32x4 ac0 = {0.f,0.f,0.f,0.f}, ac1 = ac0, ac2 = ac0;                     \
            ac0 = __builtin_amdgcn_mfma_f32_16x16x32_f16(af0, bfr[0], ac0, 0,0,0);   \
            ac1 = __builtin_amdgcn_mfma_f32_16x16x32_f16(af0, bfr[4], ac1, 0,0,0);   \
            ac2 = __builtin_amdgcn_mfma_f32_16x16x32_f16(af0, bfr[8], ac2, 0,0,0);   \
            ac0 = __builtin_amdgcn_mfma_f32_16x16x32_f16(af1, bfr[1], ac0, 0,0,0);   \
            ac1 = __builtin_amdgcn_mfma_f32_16x16x32_f16(af1, bfr[5], ac1, 0,0,0);   \
            ac2 = __builtin_amdgcn_mfma_f32_16x16x32_f16(af1, bfr[9], ac2, 0,0,0);   \
            ac0 = __builtin_amdgcn_mfma_f32_16x16x32_f16(af2, bfr[2], ac0, 0,0,0);   \
            ac1 = __builtin_amdgcn_mfma_f32_16x16x32_f16(af2, bfr[6], ac1, 0,0,0);   \
            ac2 = __builtin_amdgcn_mfma_f32_16x16x32_f16(af2, bfr[10], ac2, 0,0,0);  \
            ac0 = __builtin_amdgcn_mfma_f32_16x16x32_f16(af3, bfr[3], ac0, 0,0,0);   \
            ac1 = __builtin_amdgcn_mfma_f32_16x16x32_f16(af3, bfr[7], ac1, 0,0,0);   \
            ac2 = __builtin_amdgcn_mfma_f32_16x16x32_f16(af3, bfr[11], ac2, 0,0,0);  \
            int jg = (CH)*64 + cjl;                                                  \
            _Pragma("unroll")                                                        \
            for (int r = 0; r < 4; ++r) {                                            \
                int j = jg + r;                                                      \
                float v0 = ac0[r] + bias_s[ccol];                                    \
                if (ccol < 8) logits[ccol][j] += v0;                                 \
                else          pzl[j][ccol-8] = __float2half(v0);                     \
                pzl[j][ccol+8] = __float2half(ac1[r] + bias_s[16+ccol]);             \
                if (ccol < 8)                                                        \
                    pzl[j][ccol+24] = __float2half(ac2[r] + bias_s[32+ccol]);        \
            }                                                                        \
        }                                                                            \
        __syncthreads();                                                             \
    }

    CHUNK_BODY(0, preA)
    CHUNK_BODY(1, preB)
    CHUNK_BODY(2, preA)
    CHUNK_BODY(3, preB)
    CHUNK_BODY(4, preA)
    CHUNK_BODY(5, preB)
#undef CHUNK_BODY

    // --- softmax per head (32 lanes per head) ---
    int h = t >> 5, lnn = t & 31;
    float mx = -3.4e38f;
    #pragma unroll
    for (int jj = 0; jj < 12; ++jj) mx = fmaxf(mx, logits[h][lnn + jj*32]);
    #pragma unroll
    for (int m = 16; m >= 1; m >>= 1) mx = fmaxf(mx, __shfl_xor(mx, m, 64));
    float se = 0.f;
    #pragma unroll
    for (int jj = 0; jj < 12; ++jj) {
        int j = lnn + jj*32;
        float e = __expf(logits[h][j] - mx);
        logits[h][j] = e;
        se += e;
    }
    #pragma unroll
    for (int m = 16; m >= 1; m >>= 1) se += __shfl_xor(se, m, 64);
    float inv = 1.f / se;

    // --- pass 2: o / opt / opair accumulation; vT/vpgT coalesced dword loads ---
    float o[16], op[24], opa[32];
    #pragma unroll
    for (int d = 0; d < 16; ++d) o[d] = 0.f;
    #pragma unroll
    for (int e = 0; e < 24; ++e) op[e] = 0.f;
    #pragma unroll
    for (int c = 0; c < 32; ++c) opa[c] = 0.f;

    const float* vbase = vT + (size_t)(h*16)*BN + boff + lnn;
    const float* gbase = vpgT + (size_t)(h*24)*BN + boff + lnn;
    #pragma unroll 1
    for (int jj = 0; jj < 12; ++jj) {
        int j = lnn + jj*32;
        float wgt = logits[h][j] * inv;
        const float* vb = vbase + jj*32;
        #pragma unroll
        for (int d = 0; d < 16; ++d) o[d] = fmaf(wgt, vb[(size_t)d*BN], o[d]);
        const float* gb = gbase + jj*32;
        #pragma unroll
        for (int e = 0; e < 24; ++e) op[e] = fmaf(wgt, gb[(size_t)e*BN], op[e]);
        const __half2* pzp = reinterpret_cast<const __half2*>(&pzl[j][0]);
        #pragma unroll
        for (int c2 = 0; c2 < 16; ++c2) {
            float2 pf = __half22float2(pzp[c2]);
            opa[2*c2]   = fmaf(wgt, pf.x, opa[2*c2]);
            opa[2*c2+1] = fmaf(wgt, pf.y, opa[2*c2+1]);
        }
    }
    // butterfly reduce across the 32 lanes of this head
    #pragma unroll
    for (int m = 16; m >= 1; m >>= 1) {
        #pragma unroll
        for (int d = 0; d < 16; ++d) o[d] += __shfl_xor(o[d], m, 64);
        #pragma unroll
        for (int e = 0; e < 24; ++e) op[e] += __shfl_xor(op[e], m, 64);
        #pragma unroll
        for (int c = 0; c < 32; ++c) opa[c] += __shfl_xor(opa[c], m, 64);
    }
    if (lnn == 0) {
        float* cp = cat + (size_t)bi*640;
        #pragma unroll
        for (int d = 0; d < 16; ++d) cp[h*16 + d] = o[d];
        #pragma unroll
        for (int p = 0; p < 8; ++p) {
            float x  = op[p*3+0] - Tv[0];
            float y  = op[p*3+1] - Tv[1];
            float zz = op[p*3+2] - Tv[2];
            float l0 = Rm[0]*x + Rm[3]*y + Rm[6]*zz;   // R^T * (opt - trans)
            float l1 = Rm[1]*x + Rm[4]*y + Rm[7]*zz;
            float l2 = Rm[2]*x + Rm[5]*y + Rm[8]*zz;
            cp[128 + h*24 + p*3 + 0] = l0;
            cp[128 + h*24 + p*3 + 1] = l1;
            cp[128 + h*24 + p*3 + 2] = l2;
            cp[320 + h*8 + p] = sqrtf(l0*l0 + l1*l1 + l2*l2 + 1e-8f);
        }
        #pragma unroll
        for (int c = 0; c < 32; ++c) cp[384 + h*32 + c] = opa[c];
    }
}

// ---------------- K4: out = cat @ Wout + bout ----------------
__global__ void k_out(const float* __restrict__ cat, const float* __restrict__ Wout,
                      const float* __restrict__ bout, float* __restrict__ out) {
    __shared__ float cl[4][640];
    int t  = threadIdx.x;
    int r0 = blockIdx.x * 4;
    for (int idx = t; idx < 4*640; idx += 384)
        cl[idx/640][idx%640] = cat[(size_t)(r0 + idx/640)*640 + (idx%640)];
    __syncthreads();
    int col = t;  // 384 threads == 384 cols
    float a0=0.f, a1=0.f, a2=0.f, a3=0.f;
    for (int c = 0; c < 640; ++c) {
        float w = Wout[(size_t)c*NCS + col];
        a0 = fmaf(cl[0][c], w, a0);
        a1 = fmaf(cl[1][c], w, a1);
        a2 = fmaf(cl[2][c], w, a2);
        a3 = fmaf(cl[3][c], w, a3);
    }
    float bv = bout[col];
    out[(size_t)(r0+0)*NCS + col] = a0 + bv;
    out[(size_t)(r0+1)*NCS + col] = a1 + bv;
    out[(size_t)(r0+2)*NCS + col] = a2 + bv;
    out[(size_t)(r0+3)*NCS + col] = a3 + bv;
}

extern "C" void kernel_launch(void* const* d_in, const int* in_sizes, int n_in,
                              void* d_out, int out_size, void* d_ws, size_t ws_size,
                              hipStream_t stream) {
    const float* s    = (const float*)d_in[0];
    const float* z    = (const float*)d_in[1];
    const float* mask = (const float*)d_in[2];
    const float* rot  = (const float*)d_in[3];
    const float* trans= (const float*)d_in[4];
    const float* lm   = (const float*)d_in[5];
    const float* sc   = (const float*)d_in[6];
    const float* Wq   = (const float*)d_in[7];
    const float* Wk   = (const float*)d_in[8];
    const float* Wv   = (const float*)d_in[9];
    const float* Wb   = (const float*)d_in[10];
    const float* bb   = (const float*)d_in[11];
    const float* Wdz  = (const float*)d_in[12];
    const float* bdz  = (const float*)d_in[13];
    const float* Wqg  = (const float*)d_in[14];
    const float* bqg  = (const float*)d_in[15];
    const float* Wkg  = (const float*)d_in[16];
    const float* bkg  = (const float*)d_in[17];
    const float* Wvp  = (const float*)d_in[18];
    const float* bvp  = (const float*)d_in[19];
    const float* gsc  = (const float*)d_in[20];
    const float* gbi  = (const float*)d_in[21];
    const float* Wout = (const float*)d_in[22];
    const float* bout = (const float*)d_in[23];
    float* out = (float*)d_out;

    float* ws    = (float*)d_ws;
    float* lin   = ws;                    // 768*768 = 589824
    float* qmu   = lin   + 589824;        // 768*48  = 36864
    float* qsig  = qmu   + 36864;         // 768*96  = 73728
    float* kmuT  = qsig  + 73728;         // 48*768  = 36864
    float* ksigT = kmuT  + 36864;         // 96*768  = 73728
    float* vpgT  = ksigT + 73728;         // 192*768 = 147456
    float* kT    = vpgT  + 147456;        // 128*768 = 98304
    float* vT    = kT    + 98304;         // 128*768 = 98304
    float* cat   = vT    + 98304;         // 768*640 = 491520
    _Float16* wf = (_Float16*)(cat + 491520);   // 12*64*8 = 6144 f16

    k_wprep<<<1, 256, 0, stream>>>(Wb, Wdz, wf);
    k_rowlin<<<dim3(192, 3), 256, 0, stream>>>(s, Wq, Wk, Wv, Wqg, bqg, Wkg, bkg,
                                               Wvp, bvp, lin, kT, vT);
    k_geom<<<BN, 64, 0, stream>>>(lin, rot, trans, lm, sc, qmu, qsig, kmuT, ksigT, vpgT);
    k_attn<<<BN, 256, 0, stream>>>(z, mask, rot, trans, lin, qmu, qsig, kmuT, ksigT,
                                   kT, vT, vpgT, wf, bb, bdz, gsc, gbi, cat);
    k_out<<<192, 384, 0, stream>>>(cat, Wout, bout, out);
}